// Round 6
// baseline (703.183 us; speedup 1.0000x reference)
//
#include <hip/hip_runtime.h>

#define HH 256
#define WW 256
#define CC 3
#define KK 9
#define OC 64
#define KD 27
#define PSTS 40   // S row stride in shorts (80 B) — proven 0-conflict b128 pattern

typedef __attribute__((ext_vector_type(8))) short bf16x8;
typedef __attribute__((ext_vector_type(4))) float f32x4;

static __device__ __forceinline__ short f2bf(float f) {
    unsigned u = __float_as_uint(f);
    return (short)((u + 0x7fffu + ((u >> 16) & 1u)) >> 16);
}

// patch load (zero-padded 3x3x3) + offset/mask conv in fp32 VALU
static __device__ __forceinline__ void patch_conv(
    const float* __restrict__ xb, int i, int j,
    const float* __restrict__ wo, const float* __restrict__ bo,
    const float* __restrict__ wm, const float* __restrict__ bm,
    float* dy, float* dx, float* mz)
{
    float xv[KD];
#pragma unroll
    for (int c = 0; c < CC; ++c) {
#pragma unroll
        for (int p = 0; p < 3; ++p) {
            int y = i + p - 1;
            bool yok = (unsigned)y < HH;
#pragma unroll
            for (int q = 0; q < 3; ++q) {
                int xx = j + q - 1;
                bool ok = yok && ((unsigned)xx < WW);
                xv[c * 9 + p * 3 + q] = ok ? xb[((size_t)c * HH + y) * WW + xx] : 0.0f;
            }
        }
    }
#pragma unroll
    for (int k = 0; k < KK; ++k) {
        dy[k] = bo[2 * k];
        dx[k] = bo[2 * k + 1];
        mz[k] = bm[k];
    }
#pragma unroll
    for (int td = 0; td < KD; ++td) {
        float v = xv[td];
#pragma unroll
        for (int k = 0; k < KK; ++k) {
            dy[k] = fmaf(wo[(2 * k) * KD + td], v, dy[k]);
            dx[k] = fmaf(wo[(2 * k + 1) * KD + td], v, dx[k]);
            mz[k] = fmaf(wm[k * KD + td], v, mz[k]);
        }
    }
}

// bilinear sample of 3 channels at (i + k/3-1 + dy, j + k%3-1 + dx), no mask
static __device__ __forceinline__ void samp3(
    const float* __restrict__ xb, int i, int j, int k, float dy, float dx,
    float& r0, float& r1, float& r2)
{
    float py = (float)(i + (k / 3) - 1) + dy;
    float px = (float)(j + (k % 3) - 1) + dx;
    float y0f = floorf(py), x0f = floorf(px);
    float wy = py - y0f, wx = px - x0f;
    int y0 = (int)y0f, x0 = (int)x0f;
    int y1 = y0 + 1, x1 = x0 + 1;

    float w00 = (1.0f - wy) * (1.0f - wx);
    float w01 = (1.0f - wy) * wx;
    float w10 = wy * (1.0f - wx);
    float w11 = wy * wx;

    bool v0y = (unsigned)y0 < HH, v1y = (unsigned)y1 < HH;
    bool v0x = (unsigned)x0 < WW, v1x = (unsigned)x1 < WW;
    float f00 = (v0y && v0x) ? w00 : 0.0f;
    float f01 = (v0y && v1x) ? w01 : 0.0f;
    float f10 = (v1y && v0x) ? w10 : 0.0f;
    float f11 = (v1y && v1x) ? w11 : 0.0f;

    int y0c = min(max(y0, 0), HH - 1), y1c = min(max(y1, 0), HH - 1);
    int x0c = min(max(x0, 0), WW - 1), x1c = min(max(x1, 0), WW - 1);
    int o00 = y0c * WW + x0c, o01 = y0c * WW + x1c;
    int o10 = y1c * WW + x0c, o11 = y1c * WW + x1c;

    const float* x0p = xb;
    const float* x1p = xb + (size_t)HH * WW;
    const float* x2p = xb + (size_t)2 * HH * WW;
    r0 = x0p[o00] * f00 + x0p[o01] * f01 + x0p[o10] * f10 + x0p[o11] * f11;
    r1 = x1p[o00] * f00 + x1p[o01] * f01 + x1p[o10] * f10 + x1p[o11] * f11;
    r2 = x2p[o00] * f00 + x2p[o01] * f01 + x2p[o10] * f10 + x2p[o11] * f11;
}

__global__ __launch_bounds__(128, 3) void dcn_fused(
    const float* __restrict__ x,        // (B,3,256,256)
    const float* __restrict__ w_offset, // (18,27)
    const float* __restrict__ b_offset, // (18)
    const float* __restrict__ w_mask,   // (9,27)
    const float* __restrict__ b_mask,   // (9)
    const float* __restrict__ w_conv,   // (64,27)
    float* __restrict__ out)            // (B,64,256,256)
{
    __shared__ __align__(16) short Slds[256 * PSTS];   // 20480 B, row = column j

    const int t = threadIdx.x;          // 0..127
    const int i = blockIdx.x & (HH - 1);
    const int b = blockIdx.x >> 8;
    const int lane = t & 63;
    const int wv = t >> 6;
    const int fm = lane & 15;
    const int kc = lane >> 4;

    const float* xb = x + (size_t)b * (CC * HH * WW);

    const int jA = t;                   // pixel A
    const int jB = t + 128;             // pixel B (independent ILP stream)

    float dyA[KK], dxA[KK], mzA[KK];
    float dyB[KK], dxB[KK], mzB[KK];
    patch_conv(xb, i, jA, w_offset, b_offset, w_mask, b_mask, dyA, dxA, mzA);
    patch_conv(xb, i, jB, w_offset, b_offset, w_mask, b_mask, dyB, dxB, mzB);

    // ---- sampling: A and B interleaved per k so loads overlap ----
    float sA[KD], sB[KD];
#pragma unroll
    for (int k = 0; k < KK; ++k) {
        float a0, a1, a2, b0, b1, b2;
        samp3(xb, i, jA, k, dyA[k], dxA[k], a0, a1, a2);
        samp3(xb, i, jB, k, dyB[k], dxB[k], b0, b1, b2);
        float mA = 1.0f / (1.0f + __expf(-mzA[k]));
        float mB = 1.0f / (1.0f + __expf(-mzB[k]));
        sA[k] = a0 * mA;  sA[9 + k] = a1 * mA;  sA[18 + k] = a2 * mA;
        sB[k] = b0 * mB;  sB[9 + k] = b1 * mB;  sB[18 + k] = b2 * mB;
    }

    // ---- epilogue A-fragments (global, issue before barrier) ----
    bf16x8 afrag[4];
#pragma unroll
    for (int t2 = 0; t2 < 4; ++t2) {
#pragma unroll
        for (int e = 0; e < 8; ++e) {
            int kd = kc * 8 + e;
            int kdc = (kd < KD) ? kd : 0;
            float wv_ = w_conv[(t2 * 16 + fm) * KD + kdc];
            afrag[t2][e] = (kd < KD) ? f2bf(wv_) : (short)0;
        }
    }

    // ---- stage S rows (stride-80 b128, zero-padded to 32) ----
    {
        short* rA = Slds + jA * PSTS;
        short* rB = Slds + jB * PSTS;
#pragma unroll
        for (int o = 0; o < 4; ++o) {
            bf16x8 vA, vB;
#pragma unroll
            for (int e = 0; e < 8; ++e) {
                int kd = o * 8 + e;
                vA[e] = (kd < KD) ? f2bf(sA[kd]) : (short)0;
                vB[e] = (kd < KD) ? f2bf(sB[kd]) : (short)0;
            }
            *(bf16x8*)(rA + o * 8) = vA;
            *(bf16x8*)(rB + o * 8) = vB;
        }
    }

    __syncthreads();

    // ---- MFMA epilogue: wave wv covers pixels [wv*128, wv*128+128) ----
    float* obase = out + (size_t)b * OC * HH * WW + (size_t)i * WW;
#pragma unroll
    for (int g = 0; g < 8; ++g) {
        int jj = wv * 128 + g * 16 + fm;
        bf16x8 bfrag = *(const bf16x8*)(Slds + jj * PSTS + kc * 8);
#pragma unroll
        for (int t2 = 0; t2 < 4; ++t2) {
            f32x4 acc = (f32x4){0.f, 0.f, 0.f, 0.f};
            acc = __builtin_amdgcn_mfma_f32_16x16x32_bf16(afrag[t2], bfrag, acc, 0, 0, 0);
#pragma unroll
            for (int r = 0; r < 4; ++r) {
                obase[(size_t)(t2 * 16 + kc * 4 + r) * (HH * WW) + jj] = acc[r];
            }
        }
    }
}

extern "C" void kernel_launch(void* const* d_in, const int* in_sizes, int n_in,
                              void* d_out, int out_size, void* d_ws, size_t ws_size,
                              hipStream_t stream) {
    const float* x        = (const float*)d_in[0];
    const float* w_offset = (const float*)d_in[1];
    const float* b_offset = (const float*)d_in[2];
    const float* w_mask   = (const float*)d_in[3];
    const float* b_mask   = (const float*)d_in[4];
    const float* w_conv   = (const float*)d_in[5];
    float* out = (float*)d_out;

    int B = in_sizes[0] / (CC * HH * WW);   // 16
    dim3 grid(B * HH);                      // one block per (b, row)
    dim3 block(128);                        // 2 pixels per thread
    hipLaunchKernelGGL(dcn_fused, grid, block, 0, stream,
                       x, w_offset, b_offset, w_mask, b_mask, w_conv, out);
}

// Round 7
// 127.943 us; speedup vs baseline: 5.4960x; 5.4960x over previous
//
#include <hip/hip_runtime.h>

#define HH 256
#define WW 256
#define CC 3
#define KK 9
#define OC 64
#define KD 27
#define PSTS 40    // patch/D/S row stride in shorts (80 B) — proven 0-conflict b128 pattern
#define MOFF 5120  // mask-z region offset within per-wave LDS region (16B aligned)
#define MST 32     // mask row stride bytes (16B aligned -> b128 readback)
#define WRB 7168   // per-wave LDS bytes: 5120 (64 rows x 80B) + 2048 (64 x 32B)

typedef __attribute__((ext_vector_type(8))) short bf16x8;
typedef __attribute__((ext_vector_type(4))) float f32x4;
typedef __attribute__((ext_vector_type(2))) float f32x2;
typedef __attribute__((ext_vector_type(4))) unsigned int u32x4;

static __device__ __forceinline__ short f2bf(float f) {
    unsigned u = __float_as_uint(f);
    return (short)((u + 0x7fffu + ((u >> 16) & 1u)) >> 16);
}
static __device__ __forceinline__ unsigned pack2(short a, short b) {
    return (unsigned)(unsigned short)a | ((unsigned)(unsigned short)b << 16);
}
static __device__ __forceinline__ float bf2f(unsigned h) {   // low 16 bits -> f32
    return __uint_as_float(h << 16);
}

// ===================== prep: pack weight fragments into ws =====================
// wcf: w_conv fragments, lane l holds W[oc split][kd chunk] (32 shorts/lane, 4096 B)
// wof: offset/mask conv W hi/lo fragments + bias C-init (96 B/lane, 6144 B)
__global__ __launch_bounds__(64) void dcn_prep(
    const float* __restrict__ w_offset, const float* __restrict__ b_offset,
    const float* __restrict__ w_mask,   const float* __restrict__ b_mask,
    const float* __restrict__ w_conv,
    short* __restrict__ wcf, char* __restrict__ wof)
{
    const int tid = threadIdx.x;   // 0..63
    const int fm = tid & 15, kc = tid >> 4;
#pragma unroll
    for (int t = 0; t < 4; ++t) {
        bf16x8 v;
#pragma unroll
        for (int e = 0; e < 8; ++e) {
            int kd = kc * 8 + e;
            v[e] = (kd < KD) ? f2bf(w_conv[(t * 16 + fm) * KD + kd]) : (short)0;
        }
        *(bf16x8*)(wcf + tid * 32 + t * 8) = v;
    }
#pragma unroll
    for (int t = 0; t < 2; ++t) {
        int ch = t * 16 + fm;
        bf16x8 vh, vl;
#pragma unroll
        for (int e = 0; e < 8; ++e) {
            int kd = kc * 8 + e;
            float val = 0.0f;
            if (kd < KD) {
                if (ch < 18) val = w_offset[ch * KD + kd];
                else if (ch < KD) val = w_mask[(ch - 18) * KD + kd];
            }
            unsigned u = __float_as_uint(val);
            vh[e] = (short)(u >> 16);
            float d = val - __uint_as_float(u & 0xffff0000u);
            vl[e] = (short)(__float_as_uint(d) >> 16);
        }
        *(bf16x8*)(wof + tid * 96 + t * 16) = vh;
        *(bf16x8*)(wof + tid * 96 + 32 + t * 16) = vl;
    }
#pragma unroll
    for (int t = 0; t < 2; ++t) {
        f32x4 cb;
#pragma unroll
        for (int r = 0; r < 4; ++r) {
            int ch = t * 16 + kc * 4 + r;
            float v = 0.0f;
            if (ch < 18) v = b_offset[ch];
            else if (ch < KD) v = b_mask[ch - 18];
            cb[r] = v;
        }
        *(f32x4*)(wof + tid * 96 + 64 + t * 16) = cb;
    }
}

// ================================ main =========================================
__global__ __launch_bounds__(256) void dcn_main(
    const float* __restrict__ x,     // (B,3,256,256)
    const short* __restrict__ wcf,
    const char*  __restrict__ wof,
    float* __restrict__ out)         // (B,64,256,256)
{
    __shared__ __align__(16) char LDSBUF[4 * WRB];   // 28672 B

    const int tid = threadIdx.x;
    const int j = tid;
    const int i = blockIdx.x & (HH - 1);
    const int b = blockIdx.x >> 8;
    const int lane = tid & 63;
    const int wv = tid >> 6;
    const int fm = lane & 15;
    const int kc = lane >> 4;

    char* wbase = LDSBUF + wv * WRB;
    short* patchS = (short*)wbase;

    const float* xb = x + (size_t)b * (CC * HH * WW);

    // ---- patch: 27 coalesced f32 loads -> bf16(hi) LDS row (stride 80 B) ----
    float xv[KD];
#pragma unroll
    for (int c = 0; c < CC; ++c) {
#pragma unroll
        for (int p = 0; p < 3; ++p) {
            int y = i + p - 1;
            bool yok = (unsigned)y < HH;
#pragma unroll
            for (int q = 0; q < 3; ++q) {
                int xx = j + q - 1;
                bool ok = yok && ((unsigned)xx < WW);
                xv[c * 9 + p * 3 + q] = ok ? xb[((size_t)c * HH + y) * WW + xx] : 0.0f;
            }
        }
    }
    {
        short* rp = patchS + lane * PSTS;
#pragma unroll
        for (int o = 0; o < 4; ++o) {
            bf16x8 vh;
#pragma unroll
            for (int e = 0; e < 8; ++e) {
                int kd = o * 8 + e;
                vh[e] = (kd < KD) ? f2bf(xv[kd]) : (short)0;
            }
            *(bf16x8*)(rp + o * 8) = vh;
        }
    }

    // ---- conv W fragments + bias from prepacked ws ----
    const char* wl = wof + lane * 96;
    bf16x8 whi0 = *(const bf16x8*)(wl);
    bf16x8 whi1 = *(const bf16x8*)(wl + 16);
    bf16x8 wlo0 = *(const bf16x8*)(wl + 32);
    bf16x8 wlo1 = *(const bf16x8*)(wl + 48);
    f32x4 cb0 = *(const f32x4*)(wl + 64);
    f32x4 cb1 = *(const f32x4*)(wl + 80);

    // ---- conv MFMA: D[32ch][64px] = (Whi+Wlo)*Phi + bias ----
    // (read ALL patch rows before any D write — regions alias across lanes)
    f32x4 dacc[4][2];
#pragma unroll
    for (int g = 0; g < 4; ++g) {
        bf16x8 phi = *(const bf16x8*)(patchS + (g * 16 + fm) * PSTS + kc * 8);
        f32x4 a0 = __builtin_amdgcn_mfma_f32_16x16x32_bf16(whi0, phi, cb0, 0, 0, 0);
        a0 = __builtin_amdgcn_mfma_f32_16x16x32_bf16(wlo0, phi, a0, 0, 0, 0);
        f32x4 a1 = __builtin_amdgcn_mfma_f32_16x16x32_bf16(whi1, phi, cb1, 0, 0, 0);
        a1 = __builtin_amdgcn_mfma_f32_16x16x32_bf16(wlo1, phi, a1, 0, 0, 0);
        dacc[g][0] = a0;
        dacc[g][1] = a1;
    }
    // D rows (stride 80 B): 16 f32 dy/dx (k=0..7) + dy8,dx8 @64; mask z -> M region
#pragma unroll
    for (int g = 0; g < 4; ++g) {
        int r = g * 16 + fm;
        char* dr = wbase + r * 80;
        char* mr = wbase + MOFF + r * MST;
        *(f32x4*)(dr + kc * 16) = dacc[g][0];
        f32x4 a1 = dacc[g][1];
        if (kc == 0) {
            *(f32x2*)(dr + 64) = (f32x2){a1[0], a1[1]};                 // dy8, dx8
            *(unsigned*)(mr + 0) = pack2(f2bf(a1[2]), f2bf(a1[3]));     // z0, z1
        } else if (kc == 1) {
            *(unsigned*)(mr + 4) = pack2(f2bf(a1[0]), f2bf(a1[1]));     // z2, z3
            *(unsigned*)(mr + 8) = pack2(f2bf(a1[2]), f2bf(a1[3]));     // z4, z5
        } else if (kc == 2) {
            *(unsigned*)(mr + 12) = pack2(f2bf(a1[0]), f2bf(a1[1]));    // z6, z7
            *(unsigned short*)(mr + 16) = (unsigned short)f2bf(a1[2])   // z8
                ;
        }
    }

    // ---- read own D row + mask row fully (before S overwrites region) ----
    const char* myD = wbase + lane * 80;
    f32x4 d03 = *(const f32x4*)(myD);
    f32x4 d47 = *(const f32x4*)(myD + 16);
    f32x4 d8b = *(const f32x4*)(myD + 32);
    f32x4 dcf = *(const f32x4*)(myD + 48);
    f32x2 d8p = *(const f32x2*)(myD + 64);
    const char* myM = wbase + MOFF + lane * MST;
    u32x4 mzq = *(const u32x4*)(myM);            // z0..z7 packed
    unsigned mz8 = *(const unsigned short*)(myM + 16);

    const float dyv[9] = {d03[0], d03[2], d47[0], d47[2], d8b[0], d8b[2], dcf[0], dcf[2], d8p[0]};
    const float dxv[9] = {d03[1], d03[3], d47[1], d47[3], d8b[1], d8b[3], dcf[1], dcf[3], d8p[1]};
    const unsigned zv[9] = {mzq[0] & 0xffffu, mzq[0] >> 16, mzq[1] & 0xffffu, mzq[1] >> 16,
                            mzq[2] & 0xffffu, mzq[2] >> 16, mzq[3] & 0xffffu, mzq[3] >> 16, mz8};

    // ---- epilogue W fragments from prepacked ws (issue early, hide under gathers) ----
    bf16x8 afrag[4];
#pragma unroll
    for (int t2 = 0; t2 < 4; ++t2) afrag[t2] = *(const bf16x8*)(wcf + lane * 32 + t2 * 8);

    // ---- sampling: fp32 NCHW gathers, per-k batched ----
    const float* x0p = xb;
    const float* x1p = xb + (size_t)HH * WW;
    const float* x2p = xb + (size_t)2 * HH * WW;
    float s27[KD];
#pragma unroll
    for (int k = 0; k < KK; ++k) {
        float dy = dyv[k], dx = dxv[k];
        float msk = 1.0f / (1.0f + __expf(-bf2f(zv[k])));

        float py = (float)(i + (k / 3) - 1) + dy;
        float px = (float)(j + (k % 3) - 1) + dx;
        float y0f = floorf(py), x0f = floorf(px);
        float wy = py - y0f, wx = px - x0f;
        int y0 = (int)y0f, x0 = (int)x0f;
        int y1 = y0 + 1, x1 = x0 + 1;

        float w00 = (1.0f - wy) * (1.0f - wx);
        float w01 = (1.0f - wy) * wx;
        float w10 = wy * (1.0f - wx);
        float w11 = wy * wx;

        bool v0y = (unsigned)y0 < HH, v1y = (unsigned)y1 < HH;
        bool v0x = (unsigned)x0 < WW, v1x = (unsigned)x1 < WW;
        float f00 = (v0y && v0x) ? w00 : 0.0f;
        float f01 = (v0y && v1x) ? w01 : 0.0f;
        float f10 = (v1y && v0x) ? w10 : 0.0f;
        float f11 = (v1y && v1x) ? w11 : 0.0f;

        int y0c = min(max(y0, 0), HH - 1), y1c = min(max(y1, 0), HH - 1);
        int x0c = min(max(x0, 0), WW - 1), x1c = min(max(x1, 0), WW - 1);
        int o00 = y0c * WW + x0c, o01 = y0c * WW + x1c;
        int o10 = y1c * WW + x0c, o11 = y1c * WW + x1c;

        float r0 = x0p[o00] * f00 + x0p[o01] * f01 + x0p[o10] * f10 + x0p[o11] * f11;
        float r1 = x1p[o00] * f00 + x1p[o01] * f01 + x1p[o10] * f10 + x1p[o11] * f11;
        float r2 = x2p[o00] * f00 + x2p[o01] * f01 + x2p[o10] * f10 + x2p[o11] * f11;
        s27[k]      = r0 * msk;
        s27[9 + k]  = r1 * msk;
        s27[18 + k] = r2 * msk;
    }

    // ---- S rows: stride-80 b128 writes (own row only; wave-local ordering safe) ----
    {
        short* srow = patchS + lane * PSTS;
#pragma unroll
        for (int o = 0; o < 4; ++o) {
            bf16x8 v;
#pragma unroll
            for (int e = 0; e < 8; ++e) {
                int kd = o * 8 + e;
                v[e] = (kd < KD) ? f2bf(s27[kd]) : (short)0;
            }
            *(bf16x8*)(srow + o * 8) = v;
        }
    }

    // ---- MFMA epilogue, operand-SWAPPED: D[px][oc] -> dwordx4 stores ----
    // acc = mfma(A=S_frag(row=pixel), B=W_frag(col=oc)): lane(kc,fm) holds
    // pixels g*16+kc*4+{0..3} at oc=t2*16+fm -> 4 consecutive px = f32x4 store.
    float* obase = out + ((size_t)b * OC * HH + i) * WW;
#pragma unroll
    for (int g = 0; g < 4; ++g) {
        bf16x8 sfrag = *(const bf16x8*)(patchS + (g * 16 + fm) * PSTS + kc * 8);
#pragma unroll
        for (int t2 = 0; t2 < 4; ++t2) {
            f32x4 acc = (f32x4){0.f, 0.f, 0.f, 0.f};
            acc = __builtin_amdgcn_mfma_f32_16x16x32_bf16(sfrag, afrag[t2], acc, 0, 0, 0);
            float* op = obase + (size_t)(t2 * 16 + fm) * (HH * WW) + (wv * 64 + g * 16 + kc * 4);
            *(f32x4*)op = acc;
        }
    }
}

extern "C" void kernel_launch(void* const* d_in, const int* in_sizes, int n_in,
                              void* d_out, int out_size, void* d_ws, size_t ws_size,
                              hipStream_t stream) {
    const float* x        = (const float*)d_in[0];
    const float* w_offset = (const float*)d_in[1];
    const float* b_offset = (const float*)d_in[2];
    const float* w_mask   = (const float*)d_in[3];
    const float* b_mask   = (const float*)d_in[4];
    const float* w_conv   = (const float*)d_in[5];
    float* out = (float*)d_out;

    int B = in_sizes[0] / (CC * HH * WW);   // 16

    short* wcf = (short*)d_ws;              // 4096 B
    char*  wof = (char*)d_ws + 4096;        // 6144 B

    hipLaunchKernelGGL(dcn_prep, dim3(1), dim3(64), 0, stream,
                       w_offset, b_offset, w_mask, b_mask, w_conv, wcf, wof);
    hipLaunchKernelGGL(dcn_main, dim3(B * HH), dim3(256), 0, stream,
                       x, wcf, wof, out);
}

// Round 8
// 84.940 us; speedup vs baseline: 8.2786x; 1.5063x over previous
//
#include <hip/hip_runtime.h>

#define HH 256
#define WW 256
#define CC 3
#define KK 9
#define OC 64
#define KD 27
#define PSTS 40    // patch/D/S row stride in shorts (80 B) — proven 0-conflict b128 pattern
#define MOFF 5120  // mask-z region offset within per-wave LDS region (16B aligned)
#define MST 32     // mask row stride bytes
#define WRB 7168   // per-wave LDS bytes: 5120 (64 rows x 80B) + 2048 (64 x 32B)
#define NSC 21     // staged slot-channel rows: 7 rows x 3 channels
#define XST (4 * WRB)  // xstage offset in LDSBUF

typedef __attribute__((ext_vector_type(8))) short bf16x8;
typedef __attribute__((ext_vector_type(4))) float f32x4;
typedef __attribute__((ext_vector_type(2))) float f32x2;
typedef __attribute__((ext_vector_type(4))) unsigned int u32x4;

static __device__ __forceinline__ short f2bf(float f) {
    unsigned u = __float_as_uint(f);
    return (short)((u + 0x7fffu + ((u >> 16) & 1u)) >> 16);
}
static __device__ __forceinline__ unsigned pack2(short a, short b) {
    return (unsigned)(unsigned short)a | ((unsigned)(unsigned short)b << 16);
}
static __device__ __forceinline__ float bf2f(unsigned h) {
    return __uint_as_float(h << 16);
}

// ===================== prep: pack weight fragments into ws =====================
__global__ __launch_bounds__(64) void dcn_prep(
    const float* __restrict__ w_offset, const float* __restrict__ b_offset,
    const float* __restrict__ w_mask,   const float* __restrict__ b_mask,
    const float* __restrict__ w_conv,
    short* __restrict__ wcf, char* __restrict__ wof)
{
    const int tid = threadIdx.x;   // 0..63
    const int fm = tid & 15, kc = tid >> 4;
#pragma unroll
    for (int t = 0; t < 4; ++t) {
        bf16x8 v;
#pragma unroll
        for (int e = 0; e < 8; ++e) {
            int kd = kc * 8 + e;
            v[e] = (kd < KD) ? f2bf(w_conv[(t * 16 + fm) * KD + kd]) : (short)0;
        }
        *(bf16x8*)(wcf + tid * 32 + t * 8) = v;
    }
#pragma unroll
    for (int t = 0; t < 2; ++t) {
        int ch = t * 16 + fm;
        bf16x8 vh, vl;
#pragma unroll
        for (int e = 0; e < 8; ++e) {
            int kd = kc * 8 + e;
            float val = 0.0f;
            if (kd < KD) {
                if (ch < 18) val = w_offset[ch * KD + kd];
                else if (ch < KD) val = w_mask[(ch - 18) * KD + kd];
            }
            unsigned u = __float_as_uint(val);
            vh[e] = (short)(u >> 16);
            float d = val - __uint_as_float(u & 0xffff0000u);
            vl[e] = (short)(__float_as_uint(d) >> 16);
        }
        *(bf16x8*)(wof + tid * 96 + t * 16) = vh;
        *(bf16x8*)(wof + tid * 96 + 32 + t * 16) = vl;
    }
#pragma unroll
    for (int t = 0; t < 2; ++t) {
        f32x4 cb;
#pragma unroll
        for (int r = 0; r < 4; ++r) {
            int ch = t * 16 + kc * 4 + r;
            float v = 0.0f;
            if (ch < 18) v = b_offset[ch];
            else if (ch < KD) v = b_mask[ch - 18];
            cb[r] = v;
        }
        *(f32x4*)(wof + tid * 96 + 64 + t * 16) = cb;
    }
}

// ================================ main =========================================
__global__ __launch_bounds__(256) void dcn_main(
    const float* __restrict__ x,     // (B,3,256,256)
    const short* __restrict__ wcf,
    const char*  __restrict__ wof,
    float* __restrict__ out)         // (B,64,256,256)
{
    __shared__ __align__(16) char LDSBUF[XST + NSC * 256 * 4];   // 28672 + 21504 = 50176 B

    const int tid = threadIdx.x;
    const int j = tid;
    const int i = blockIdx.x & (HH - 1);
    const int b = blockIdx.x >> 8;
    const int lane = tid & 63;
    const int wv = tid >> 6;
    const int fm = lane & 15;
    const int kc = lane >> 4;

    char* wbase = LDSBUF + wv * WRB;
    short* patchS = (short*)wbase;
    float* xstage = (float*)(LDSBUF + XST);   // [7 slots][3 ch][256 cols] f32

    const float* xb = x + (size_t)b * (CC * HH * WW);

    // ---- phase 0: cooperative stage of rows i-3..i+3 (clamped), f32 ----
#pragma unroll
    for (int t = 0; t < NSC; ++t) {
        int s = t / 3, c = t - s * 3;
        int gr = min(max(i - 3 + s, 0), HH - 1);
        xstage[t * 256 + tid] = xb[(size_t)c * (HH * WW) + gr * WW + tid];
    }
    __syncthreads();

    // ---- patch from LDS (zero-padded at image borders) ----
    float xv[KD];
#pragma unroll
    for (int c = 0; c < CC; ++c) {
#pragma unroll
        for (int p = 0; p < 3; ++p) {
            int yy = i + p - 1;
            bool yok = (unsigned)yy < HH;
            const float* row = xstage + ((p + 2) * 3 + c) * 256;
#pragma unroll
            for (int q = 0; q < 3; ++q) {
                int xx = j + q - 1;
                bool ok = yok && ((unsigned)xx < WW);
                int xcl = min(max(xx, 0), WW - 1);
                float v = row[xcl];
                xv[c * 9 + p * 3 + q] = ok ? v : 0.0f;
            }
        }
    }
    {
        short* rp = patchS + lane * PSTS;
#pragma unroll
        for (int o = 0; o < 4; ++o) {
            bf16x8 vh;
#pragma unroll
            for (int e = 0; e < 8; ++e) {
                int kd = o * 8 + e;
                vh[e] = (kd < KD) ? f2bf(xv[kd]) : (short)0;
            }
            *(bf16x8*)(rp + o * 8) = vh;
        }
    }

    // ---- conv W fragments + bias from prepacked ws ----
    const char* wl = wof + lane * 96;
    bf16x8 whi0 = *(const bf16x8*)(wl);
    bf16x8 whi1 = *(const bf16x8*)(wl + 16);
    bf16x8 wlo0 = *(const bf16x8*)(wl + 32);
    bf16x8 wlo1 = *(const bf16x8*)(wl + 48);
    f32x4 cb0 = *(const f32x4*)(wl + 64);
    f32x4 cb1 = *(const f32x4*)(wl + 80);

    // ---- conv MFMA: D[32ch][64px] = (Whi+Wlo)*Phi + bias ----
    f32x4 dacc[4][2];
#pragma unroll
    for (int g = 0; g < 4; ++g) {
        bf16x8 phi = *(const bf16x8*)(patchS + (g * 16 + fm) * PSTS + kc * 8);
        f32x4 a0 = __builtin_amdgcn_mfma_f32_16x16x32_bf16(whi0, phi, cb0, 0, 0, 0);
        a0 = __builtin_amdgcn_mfma_f32_16x16x32_bf16(wlo0, phi, a0, 0, 0, 0);
        f32x4 a1 = __builtin_amdgcn_mfma_f32_16x16x32_bf16(whi1, phi, cb1, 0, 0, 0);
        a1 = __builtin_amdgcn_mfma_f32_16x16x32_bf16(wlo1, phi, a1, 0, 0, 0);
        dacc[g][0] = a0;
        dacc[g][1] = a1;
    }
#pragma unroll
    for (int g = 0; g < 4; ++g) {
        int r = g * 16 + fm;
        char* dr = wbase + r * 80;
        char* mr = wbase + MOFF + r * MST;
        *(f32x4*)(dr + kc * 16) = dacc[g][0];
        f32x4 a1 = dacc[g][1];
        if (kc == 0) {
            *(f32x2*)(dr + 64) = (f32x2){a1[0], a1[1]};
            *(unsigned*)(mr + 0) = pack2(f2bf(a1[2]), f2bf(a1[3]));
        } else if (kc == 1) {
            *(unsigned*)(mr + 4) = pack2(f2bf(a1[0]), f2bf(a1[1]));
            *(unsigned*)(mr + 8) = pack2(f2bf(a1[2]), f2bf(a1[3]));
        } else if (kc == 2) {
            *(unsigned*)(mr + 12) = pack2(f2bf(a1[0]), f2bf(a1[1]));
            *(unsigned short*)(mr + 16) = (unsigned short)f2bf(a1[2]);
        }
    }

    // ---- read own D row + mask row fully (before S overwrites region) ----
    const char* myD = wbase + lane * 80;
    f32x4 d03 = *(const f32x4*)(myD);
    f32x4 d47 = *(const f32x4*)(myD + 16);
    f32x4 d8b = *(const f32x4*)(myD + 32);
    f32x4 dcf = *(const f32x4*)(myD + 48);
    f32x2 d8p = *(const f32x2*)(myD + 64);
    const char* myM = wbase + MOFF + lane * MST;
    u32x4 mzq = *(const u32x4*)(myM);
    unsigned mz8 = *(const unsigned short*)(myM + 16);

    const float dyv[9] = {d03[0], d03[2], d47[0], d47[2], d8b[0], d8b[2], dcf[0], dcf[2], d8p[0]};
    const float dxv[9] = {d03[1], d03[3], d47[1], d47[3], d8b[1], d8b[3], dcf[1], dcf[3], d8p[1]};
    const unsigned zv[9] = {mzq[0] & 0xffffu, mzq[0] >> 16, mzq[1] & 0xffffu, mzq[1] >> 16,
                            mzq[2] & 0xffffu, mzq[2] >> 16, mzq[3] & 0xffffu, mzq[3] >> 16, mz8};

    // ---- epilogue W fragments (issue early) ----
    bf16x8 afrag[4];
#pragma unroll
    for (int t2 = 0; t2 < 4; ++t2) afrag[t2] = *(const bf16x8*)(wcf + lane * 32 + t2 * 8);

    // ---- sampling: LDS gathers (fast) with rare global fallback ----
    const float* x0p = xb;
    const float* x1p = xb + (size_t)HH * WW;
    const float* x2p = xb + (size_t)2 * HH * WW;
    float s27[KD];
#pragma unroll
    for (int k = 0; k < KK; ++k) {
        float dy = dyv[k], dx = dxv[k];
        float msk = 1.0f / (1.0f + __expf(-bf2f(zv[k])));

        float py = (float)(i + (k / 3) - 1) + dy;
        float px = (float)(j + (k % 3) - 1) + dx;
        float y0f = floorf(py), x0f = floorf(px);
        float wy = py - y0f, wx = px - x0f;
        int y0 = (int)y0f, x0 = (int)x0f;
        int y1 = y0 + 1, x1 = x0 + 1;

        float w00 = (1.0f - wy) * (1.0f - wx);
        float w01 = (1.0f - wy) * wx;
        float w10 = wy * (1.0f - wx);
        float w11 = wy * wx;

        bool v0y = (unsigned)y0 < HH, v1y = (unsigned)y1 < HH;
        bool v0x = (unsigned)x0 < WW, v1x = (unsigned)x1 < WW;
        float f00 = (v0y && v0x) ? w00 : 0.0f;
        float f01 = (v0y && v1x) ? w01 : 0.0f;
        float f10 = (v1y && v0x) ? w10 : 0.0f;
        float f11 = (v1y && v1x) ? w11 : 0.0f;

        int y0c = min(max(y0, 0), HH - 1), y1c = min(max(y1, 0), HH - 1);

        int s0 = y0c - i + 3;
        int s1 = y1c - i + 3;
        float r0, r1, r2;
        if (__builtin_expect(__any(((unsigned)s0 > 6u) || ((unsigned)s1 > 6u)), 0)) {
            // ---- slow path: global gather (exact original semantics) ----
            int x0c = min(max(x0, 0), WW - 1), x1c = min(max(x1, 0), WW - 1);
            int o00 = y0c * WW + x0c, o01 = y0c * WW + x1c;
            int o10 = y1c * WW + x0c, o11 = y1c * WW + x1c;
            r0 = x0p[o00] * f00 + x0p[o01] * f01 + x0p[o10] * f10 + x0p[o11] * f11;
            r1 = x1p[o00] * f00 + x1p[o01] * f01 + x1p[o10] * f10 + x1p[o11] * f11;
            r2 = x2p[o00] * f00 + x2p[o01] * f01 + x2p[o10] * f10 + x2p[o11] * f11;
        } else {
            // ---- fast path: LDS pair reads; clamped-x mapped via zero weights ----
            int xl = min(max(x0, 0), WW - 2);
            bool xnorm = (x0 == xl);
            int b0 = s0 * 3 * 256 + xl;
            int b1 = s1 * 3 * 256 + xl;

            float lo0c0 = xstage[b0],        hi0c0 = xstage[b0 + 1];
            float lo1c0 = xstage[b1],        hi1c0 = xstage[b1 + 1];
            float lo0c1 = xstage[b0 + 256],  hi0c1 = xstage[b0 + 257];
            float lo1c1 = xstage[b1 + 256],  hi1c1 = xstage[b1 + 257];
            float lo0c2 = xstage[b0 + 512],  hi0c2 = xstage[b0 + 513];
            float lo1c2 = xstage[b1 + 512],  hi1c2 = xstage[b1 + 513];

            float v00, v01, v10, v11;
            v00 = xnorm ? lo0c0 : hi0c0;  v01 = xnorm ? hi0c0 : lo0c0;
            v10 = xnorm ? lo1c0 : hi1c0;  v11 = xnorm ? hi1c0 : lo1c0;
            r0 = v00 * f00 + v01 * f01 + v10 * f10 + v11 * f11;
            v00 = xnorm ? lo0c1 : hi0c1;  v01 = xnorm ? hi0c1 : lo0c1;
            v10 = xnorm ? lo1c1 : hi1c1;  v11 = xnorm ? hi1c1 : lo1c1;
            r1 = v00 * f00 + v01 * f01 + v10 * f10 + v11 * f11;
            v00 = xnorm ? lo0c2 : hi0c2;  v01 = xnorm ? hi0c2 : lo0c2;
            v10 = xnorm ? lo1c2 : hi1c2;  v11 = xnorm ? hi1c2 : lo1c2;
            r2 = v00 * f00 + v01 * f01 + v10 * f10 + v11 * f11;
        }
        s27[k]      = r0 * msk;
        s27[9 + k]  = r1 * msk;
        s27[18 + k] = r2 * msk;
    }

    // ---- S rows: stride-80 b128 writes ----
    {
        short* srow = patchS + lane * PSTS;
#pragma unroll
        for (int o = 0; o < 4; ++o) {
            bf16x8 v;
#pragma unroll
            for (int e = 0; e < 8; ++e) {
                int kd = o * 8 + e;
                v[e] = (kd < KD) ? f2bf(s27[kd]) : (short)0;
            }
            *(bf16x8*)(srow + o * 8) = v;
        }
    }

    // ---- MFMA epilogue, operand-swapped: 4 consecutive px per lane -> dwordx4 ----
    float* obase = out + ((size_t)b * OC * HH + i) * WW;
#pragma unroll
    for (int g = 0; g < 4; ++g) {
        bf16x8 sfrag = *(const bf16x8*)(patchS + (g * 16 + fm) * PSTS + kc * 8);
#pragma unroll
        for (int t2 = 0; t2 < 4; ++t2) {
            f32x4 acc = (f32x4){0.f, 0.f, 0.f, 0.f};
            acc = __builtin_amdgcn_mfma_f32_16x16x32_bf16(sfrag, afrag[t2], acc, 0, 0, 0);
            float* op = obase + (size_t)(t2 * 16 + fm) * (HH * WW) + (wv * 64 + g * 16 + kc * 4);
            *(f32x4*)op = acc;
        }
    }
}

extern "C" void kernel_launch(void* const* d_in, const int* in_sizes, int n_in,
                              void* d_out, int out_size, void* d_ws, size_t ws_size,
                              hipStream_t stream) {
    const float* x        = (const float*)d_in[0];
    const float* w_offset = (const float*)d_in[1];
    const float* b_offset = (const float*)d_in[2];
    const float* w_mask   = (const float*)d_in[3];
    const float* b_mask   = (const float*)d_in[4];
    const float* w_conv   = (const float*)d_in[5];
    float* out = (float*)d_out;

    int B = in_sizes[0] / (CC * HH * WW);   // 16

    short* wcf = (short*)d_ws;              // 4096 B
    char*  wof = (char*)d_ws + 4096;        // 6144 B

    hipLaunchKernelGGL(dcn_prep, dim3(1), dim3(64), 0, stream,
                       w_offset, b_offset, w_mask, b_mask, w_conv, wcf, wof);
    hipLaunchKernelGGL(dcn_main, dim3(B * HH), dim3(256), 0, stream,
                       x, wcf, wof, out);
}

// Round 9
// 78.664 us; speedup vs baseline: 8.9391x; 1.0798x over previous
//
#include <hip/hip_runtime.h>

#define HH 256
#define WW 256
#define CC 3
#define KK 9
#define OC 64
#define KD 27
#define PSTS 40    // patch/D/S row stride in shorts (80 B) — proven 0-conflict b128 pattern
#define MOFF 5120  // mask-z region offset within per-wave LDS region
#define MST 16     // mask row stride bytes (z4..z8, 10 B used)
#define WRB 6144   // per-wave LDS bytes: 5120 (64 x 80B) + 1024 (64 x 16B)
#define XST (4 * WRB)   // xstage offset in LDSBUF = 24576
#define XSLOT 1024      // shorts per staged slot (256 px * 4 shorts)

typedef __attribute__((ext_vector_type(8))) short bf16x8;
typedef __attribute__((ext_vector_type(4))) short s16x4;
typedef __attribute__((ext_vector_type(4))) float f32x4;
typedef __attribute__((ext_vector_type(2))) float f32x2;
typedef __attribute__((ext_vector_type(2))) unsigned int u32x2;

static __device__ __forceinline__ short f2bf(float f) {
    unsigned u = __float_as_uint(f);
    return (short)((u + 0x7fffu + ((u >> 16) & 1u)) >> 16);
}
static __device__ __forceinline__ unsigned pack2(short a, short b) {
    return (unsigned)(unsigned short)a | ((unsigned)(unsigned short)b << 16);
}
static __device__ __forceinline__ float bf2f(unsigned w) {   // low 16 bits
    return __uint_as_float(w << 16);
}
static __device__ __forceinline__ float bfup(unsigned w) {   // high 16 bits
    return __uint_as_float(w & 0xffff0000u);
}

// ===================== prep: pack weight fragments into ws =====================
__global__ __launch_bounds__(64) void dcn_prep(
    const float* __restrict__ w_offset, const float* __restrict__ b_offset,
    const float* __restrict__ w_mask,   const float* __restrict__ b_mask,
    const float* __restrict__ w_conv,
    short* __restrict__ wcf, char* __restrict__ wof)
{
    const int tid = threadIdx.x;   // 0..63
    const int fm = tid & 15, kc = tid >> 4;
#pragma unroll
    for (int t = 0; t < 4; ++t) {
        bf16x8 v;
#pragma unroll
        for (int e = 0; e < 8; ++e) {
            int kd = kc * 8 + e;
            v[e] = (kd < KD) ? f2bf(w_conv[(t * 16 + fm) * KD + kd]) : (short)0;
        }
        *(bf16x8*)(wcf + tid * 32 + t * 8) = v;
    }
#pragma unroll
    for (int t = 0; t < 2; ++t) {
        int ch = t * 16 + fm;
        bf16x8 vh, vl;
#pragma unroll
        for (int e = 0; e < 8; ++e) {
            int kd = kc * 8 + e;
            float val = 0.0f;
            if (kd < KD) {
                if (ch < 18) val = w_offset[ch * KD + kd];
                else if (ch < KD) val = w_mask[(ch - 18) * KD + kd];
            }
            unsigned u = __float_as_uint(val);
            vh[e] = (short)(u >> 16);
            float d = val - __uint_as_float(u & 0xffff0000u);
            vl[e] = (short)(__float_as_uint(d) >> 16);
        }
        *(bf16x8*)(wof + tid * 96 + t * 16) = vh;
        *(bf16x8*)(wof + tid * 96 + 32 + t * 16) = vl;
    }
#pragma unroll
    for (int t = 0; t < 2; ++t) {
        f32x4 cb;
#pragma unroll
        for (int r = 0; r < 4; ++r) {
            int ch = t * 16 + kc * 4 + r;
            float v = 0.0f;
            if (ch < 18) v = b_offset[ch];
            else if (ch < KD) v = b_mask[ch - 18];
            cb[r] = v;
        }
        *(f32x4*)(wof + tid * 96 + 64 + t * 16) = cb;
    }
}

// ================================ main =========================================
__global__ __launch_bounds__(256) void dcn_main(
    const float* __restrict__ x,     // (B,3,256,256)
    const short* __restrict__ wcf,
    const char*  __restrict__ wof,
    float* __restrict__ out)         // (B,64,256,256)
{
    __shared__ __align__(16) char LDSBUF[XST + 7 * XSLOT * 2];   // 24576 + 14336 = 38912 B

    const int tid = threadIdx.x;
    const int j = tid;
    const int i = blockIdx.x & (HH - 1);
    const int b = blockIdx.x >> 8;
    const int lane = tid & 63;
    const int wv = tid >> 6;
    const int fm = lane & 15;
    const int kc = lane >> 4;

    char* wbase = LDSBUF + wv * WRB;
    short* patchS = (short*)wbase;
    short* xs = (short*)(LDSBUF + XST);   // [7 slots][256 px][4 shorts] bf16, px-major

    const float* xb = x + (size_t)b * (CC * HH * WW);

    // ---- phase 0: cooperative stage rows i-3..i+3 (clamped), px-major bf16 ----
#pragma unroll
    for (int s = 0; s < 7; ++s) {
        int gr = min(max(i - 3 + s, 0), HH - 1);
        const float* rp = xb + (size_t)gr * WW + tid;
        float c0 = rp[0];
        float c1 = rp[HH * WW];
        float c2 = rp[2 * HH * WW];
        s16x4 v = {f2bf(c0), f2bf(c1), f2bf(c2), 0};
        *(s16x4*)(xs + s * XSLOT + tid * 4) = v;
    }
    __syncthreads();

    // ---- patch from LDS (9 b64 reads), zero-padded at image borders ----
    const bool yok0 = (i - 1) >= 0, yok2 = (i + 1) < HH;
    const bool xok0 = (j - 1) >= 0, xok2 = (j + 1) < WW;
    s16x4 pr[3][3];
#pragma unroll
    for (int p = 0; p < 3; ++p) {
#pragma unroll
        for (int q = 0; q < 3; ++q) {
            int xx = min(max(j + q - 1, 0), WW - 1);
            pr[p][q] = *(const s16x4*)(xs + (p + 2) * XSLOT + xx * 4);
        }
    }
    {
        short* rp = patchS + lane * PSTS;
#pragma unroll
        for (int o = 0; o < 4; ++o) {
            bf16x8 vh;
#pragma unroll
            for (int e = 0; e < 8; ++e) {
                int kd = o * 8 + e;
                if (kd < KD) {
                    int c = kd / 9, rem = kd - c * 9, p = rem / 3, q = rem - p * 3;
                    bool ok = (p == 0 ? yok0 : (p == 2 ? yok2 : true)) &&
                              (q == 0 ? xok0 : (q == 2 ? xok2 : true));
                    vh[e] = ok ? pr[p][q][c] : (short)0;
                } else {
                    vh[e] = (short)0;
                }
            }
            *(bf16x8*)(rp + o * 8) = vh;
        }
    }

    // ---- conv W fragments + bias from prepacked ws ----
    const char* wl = wof + lane * 96;
    bf16x8 whi0 = *(const bf16x8*)(wl);
    bf16x8 whi1 = *(const bf16x8*)(wl + 16);
    bf16x8 wlo0 = *(const bf16x8*)(wl + 32);
    bf16x8 wlo1 = *(const bf16x8*)(wl + 48);
    f32x4 cb0 = *(const f32x4*)(wl + 64);
    f32x4 cb1 = *(const f32x4*)(wl + 80);

    // ---- conv MFMA: D[32ch][64px] = (Whi+Wlo)*Phi + bias ----
    f32x4 dacc[4][2];
#pragma unroll
    for (int g = 0; g < 4; ++g) {
        bf16x8 phi = *(const bf16x8*)(patchS + (g * 16 + fm) * PSTS + kc * 8);
        f32x4 a0 = __builtin_amdgcn_mfma_f32_16x16x32_bf16(whi0, phi, cb0, 0, 0, 0);
        a0 = __builtin_amdgcn_mfma_f32_16x16x32_bf16(wlo0, phi, a0, 0, 0, 0);
        f32x4 a1 = __builtin_amdgcn_mfma_f32_16x16x32_bf16(whi1, phi, cb1, 0, 0, 0);
        a1 = __builtin_amdgcn_mfma_f32_16x16x32_bf16(wlo1, phi, a1, 0, 0, 0);
        dacc[g][0] = a0;
        dacc[g][1] = a1;
    }
    // D rows (80 B): 16 f32 dy/dx + dy8,dx8 @64 + z0..z3 @72; z4..z8 in M region
#pragma unroll
    for (int g = 0; g < 4; ++g) {
        int r = g * 16 + fm;
        char* dr = wbase + r * 80;
        char* mr = wbase + MOFF + r * MST;
        *(f32x4*)(dr + kc * 16) = dacc[g][0];
        f32x4 a1 = dacc[g][1];
        if (kc == 0) {
            *(f32x2*)(dr + 64) = (f32x2){a1[0], a1[1]};                 // dy8, dx8
            *(unsigned*)(dr + 72) = pack2(f2bf(a1[2]), f2bf(a1[3]));    // z0, z1
        } else if (kc == 1) {
            *(unsigned*)(dr + 76) = pack2(f2bf(a1[0]), f2bf(a1[1]));    // z2, z3
            *(unsigned*)(mr + 0) = pack2(f2bf(a1[2]), f2bf(a1[3]));     // z4, z5
        } else if (kc == 2) {
            *(unsigned*)(mr + 4) = pack2(f2bf(a1[0]), f2bf(a1[1]));     // z6, z7
            *(unsigned short*)(mr + 8) = (unsigned short)f2bf(a1[2]);   // z8
        }
    }

    // ---- read own D row + mask row fully (before S overwrites region) ----
    const char* myD = wbase + lane * 80;
    f32x4 d03 = *(const f32x4*)(myD);
    f32x4 d47 = *(const f32x4*)(myD + 16);
    f32x4 d8b = *(const f32x4*)(myD + 32);
    f32x4 dcf = *(const f32x4*)(myD + 48);
    f32x2 d8p = *(const f32x2*)(myD + 64);
    u32x2 z03 = *(const u32x2*)(myD + 72);                       // z0z1, z2z3
    const char* myM = wbase + MOFF + lane * MST;
    u32x2 z47 = *(const u32x2*)(myM);                            // z4z5, z6z7
    unsigned z8w = *(const unsigned short*)(myM + 8);

    const float dyv[9] = {d03[0], d03[2], d47[0], d47[2], d8b[0], d8b[2], dcf[0], dcf[2], d8p[0]};
    const float dxv[9] = {d03[1], d03[3], d47[1], d47[3], d8b[1], d8b[3], dcf[1], dcf[3], d8p[1]};
    const float mzf[9] = {bf2f(z03.x), bfup(z03.x), bf2f(z03.y), bfup(z03.y),
                          bf2f(z47.x), bfup(z47.x), bf2f(z47.y), bfup(z47.y), bf2f(z8w)};

    // ---- epilogue W fragments (issue early) ----
    bf16x8 afrag[4];
#pragma unroll
    for (int t2 = 0; t2 < 4; ++t2) afrag[t2] = *(const bf16x8*)(wcf + lane * 32 + t2 * 8);

    // ---- sampling: px-major bf16 LDS reads (fast) with rare global fallback ----
    const float* x0p = xb;
    const float* x1p = xb + (size_t)HH * WW;
    const float* x2p = xb + (size_t)2 * HH * WW;
    float s27[KD];
#pragma unroll
    for (int k = 0; k < KK; ++k) {
        float dy = dyv[k], dx = dxv[k];
        float msk = 1.0f / (1.0f + __expf(-mzf[k]));

        float py = (float)(i + (k / 3) - 1) + dy;
        float px = (float)(j + (k % 3) - 1) + dx;
        float y0f = floorf(py), x0f = floorf(px);
        float wy = py - y0f, wx = px - x0f;
        int y0 = (int)y0f, x0 = (int)x0f;
        int y1 = y0 + 1, x1 = x0 + 1;

        float w00 = (1.0f - wy) * (1.0f - wx);
        float w01 = (1.0f - wy) * wx;
        float w10 = wy * (1.0f - wx);
        float w11 = wy * wx;

        bool v0y = (unsigned)y0 < HH, v1y = (unsigned)y1 < HH;
        bool v0x = (unsigned)x0 < WW, v1x = (unsigned)x1 < WW;
        float f00 = (v0y && v0x) ? w00 : 0.0f;
        float f01 = (v0y && v1x) ? w01 : 0.0f;
        float f10 = (v1y && v0x) ? w10 : 0.0f;
        float f11 = (v1y && v1x) ? w11 : 0.0f;

        int y0c = min(max(y0, 0), HH - 1), y1c = min(max(y1, 0), HH - 1);
        int s0 = y0c - i + 3;
        int s1 = y1c - i + 3;
        float r0, r1, r2;
        if (__builtin_expect(__any(((unsigned)s0 > 6u) || ((unsigned)s1 > 6u)), 0)) {
            // ---- slow path: global f32 gather (exact semantics) ----
            int x0c = min(max(x0, 0), WW - 1), x1c = min(max(x1, 0), WW - 1);
            int o00 = y0c * WW + x0c, o01 = y0c * WW + x1c;
            int o10 = y1c * WW + x0c, o11 = y1c * WW + x1c;
            r0 = x0p[o00] * f00 + x0p[o01] * f01 + x0p[o10] * f10 + x0p[o11] * f11;
            r1 = x1p[o00] * f00 + x1p[o01] * f01 + x1p[o10] * f10 + x1p[o11] * f11;
            r2 = x2p[o00] * f00 + x2p[o01] * f01 + x2p[o10] * f10 + x2p[o11] * f11;
        } else {
            // ---- fast path: 4 x 8B LDS reads; clamped-x handled by weight swap ----
            int xl = min(max(x0, 0), WW - 2);
            bool sw = (x0 != xl);
            const short* p0 = xs + s0 * XSLOT + xl * 4;
            const short* p1 = xs + s1 * XSLOT + xl * 4;
            u32x2 lo0 = *(const u32x2*)p0;
            u32x2 hi0 = *(const u32x2*)(p0 + 4);
            u32x2 lo1 = *(const u32x2*)p1;
            u32x2 hi1 = *(const u32x2*)(p1 + 4);

            float a0 = sw ? f01 : f00, b0 = sw ? f00 : f01;   // weights for (lo, hi)
            float a1w = sw ? f11 : f10, b1w = sw ? f10 : f11;

            r0 = fmaf(bf2f(lo0.x), a0, fmaf(bf2f(hi0.x), b0,
                 fmaf(bf2f(lo1.x), a1w, bf2f(hi1.x) * b1w)));
            r1 = fmaf(bfup(lo0.x), a0, fmaf(bfup(hi0.x), b0,
                 fmaf(bfup(lo1.x), a1w, bfup(hi1.x) * b1w)));
            r2 = fmaf(bf2f(lo0.y), a0, fmaf(bf2f(hi0.y), b0,
                 fmaf(bf2f(lo1.y), a1w, bf2f(hi1.y) * b1w)));
        }
        s27[k]      = r0 * msk;
        s27[9 + k]  = r1 * msk;
        s27[18 + k] = r2 * msk;
    }

    // ---- S rows: stride-80 b128 writes ----
    {
        short* srow = patchS + lane * PSTS;
#pragma unroll
        for (int o = 0; o < 4; ++o) {
            bf16x8 v;
#pragma unroll
            for (int e = 0; e < 8; ++e) {
                int kd = o * 8 + e;
                v[e] = (kd < KD) ? f2bf(s27[kd]) : (short)0;
            }
            *(bf16x8*)(srow + o * 8) = v;
        }
    }

    // ---- MFMA epilogue, operand-swapped: 4 consecutive px per lane -> dwordx4 ----
    float* obase = out + ((size_t)b * OC * HH + i) * WW;
#pragma unroll
    for (int g = 0; g < 4; ++g) {
        bf16x8 sfrag = *(const bf16x8*)(patchS + (g * 16 + fm) * PSTS + kc * 8);
#pragma unroll
        for (int t2 = 0; t2 < 4; ++t2) {
            f32x4 acc = (f32x4){0.f, 0.f, 0.f, 0.f};
            acc = __builtin_amdgcn_mfma_f32_16x16x32_bf16(sfrag, afrag[t2], acc, 0, 0, 0);
            float* op = obase + (size_t)(t2 * 16 + fm) * (HH * WW) + (wv * 64 + g * 16 + kc * 4);
            *(f32x4*)op = acc;
        }
    }
}

extern "C" void kernel_launch(void* const* d_in, const int* in_sizes, int n_in,
                              void* d_out, int out_size, void* d_ws, size_t ws_size,
                              hipStream_t stream) {
    const float* x        = (const float*)d_in[0];
    const float* w_offset = (const float*)d_in[1];
    const float* b_offset = (const float*)d_in[2];
    const float* w_mask   = (const float*)d_in[3];
    const float* b_mask   = (const float*)d_in[4];
    const float* w_conv   = (const float*)d_in[5];
    float* out = (float*)d_out;

    int B = in_sizes[0] / (CC * HH * WW);   // 16

    short* wcf = (short*)d_ws;              // 4096 B
    char*  wof = (char*)d_ws + 4096;        // 6144 B

    hipLaunchKernelGGL(dcn_prep, dim3(1), dim3(64), 0, stream,
                       w_offset, b_offset, w_mask, b_mask, w_conv, wcf, wof);
    hipLaunchKernelGGL(dcn_main, dim3(B * HH), dim3(256), 0, stream,
                       x, wcf, wof, out);
}

// Round 10
// 75.837 us; speedup vs baseline: 9.2723x; 1.0373x over previous
//
#include <hip/hip_runtime.h>
#include <hip/hip_bf16.h>

#define HH 256
#define WW 256
#define CC 3
#define KK 9
#define OC 64
#define KD 27
#define PSTS 40    // patch/D/S row stride in shorts (80 B) — proven 0-conflict b128 pattern
#define MOFF 5120  // mask-z region offset within per-wave LDS region
#define MST 16     // mask row stride bytes (z4..z8, 10 B used)
#define WRB 6144   // per-wave LDS bytes: 5120 (64 x 80B) + 1024 (64 x 16B)
#define XST (4 * WRB)   // xstage offset in LDSBUF = 24576
#define XSLOT 1024      // shorts per staged slot (256 px * 4 shorts)

typedef __attribute__((ext_vector_type(8))) short bf16x8;
typedef __attribute__((ext_vector_type(4))) short s16x4;
typedef __attribute__((ext_vector_type(4))) float f32x4;
typedef __attribute__((ext_vector_type(2))) float f32x2;
typedef __attribute__((ext_vector_type(2))) unsigned int u32x2;

// hardware RNE f32 -> bf16 (single v_cvt instr; identical rounding to manual RNE)
static __device__ __forceinline__ short f2bf(float f) {
    __hip_bfloat16 h = __float2bfloat16(f);
    return __builtin_bit_cast(short, h);
}
static __device__ __forceinline__ unsigned pack2(short a, short b) {
    return (unsigned)(unsigned short)a | ((unsigned)(unsigned short)b << 16);
}
static __device__ __forceinline__ float bf2f(unsigned w) {   // low 16 bits
    return __uint_as_float(w << 16);
}
static __device__ __forceinline__ float bfup(unsigned w) {   // high 16 bits
    return __uint_as_float(w & 0xffff0000u);
}

// ===================== prep: bf16 pixel-major x copy + weight fragments ========
__global__ __launch_bounds__(256) void dcn_prep(
    const float* __restrict__ x,
    const float* __restrict__ w_offset, const float* __restrict__ b_offset,
    const float* __restrict__ w_mask,   const float* __restrict__ b_mask,
    const float* __restrict__ w_conv,
    short* __restrict__ xbf, short* __restrict__ wcf, char* __restrict__ wof,
    int npix)
{
    const int tid = threadIdx.x;
    if (blockIdx.x == gridDim.x - 1) {
        if (tid < 64) {
            const int fm = tid & 15, kc = tid >> 4;
#pragma unroll
            for (int t = 0; t < 4; ++t) {
                bf16x8 v;
#pragma unroll
                for (int e = 0; e < 8; ++e) {
                    int kd = kc * 8 + e;
                    v[e] = (kd < KD) ? f2bf(w_conv[(t * 16 + fm) * KD + kd]) : (short)0;
                }
                *(bf16x8*)(wcf + tid * 32 + t * 8) = v;
            }
#pragma unroll
            for (int t = 0; t < 2; ++t) {
                int ch = t * 16 + fm;
                bf16x8 vh, vl;
#pragma unroll
                for (int e = 0; e < 8; ++e) {
                    int kd = kc * 8 + e;
                    float val = 0.0f;
                    if (kd < KD) {
                        if (ch < 18) val = w_offset[ch * KD + kd];
                        else if (ch < KD) val = w_mask[(ch - 18) * KD + kd];
                    }
                    unsigned u = __float_as_uint(val);
                    vh[e] = (short)(u >> 16);
                    float d = val - __uint_as_float(u & 0xffff0000u);
                    vl[e] = (short)(__float_as_uint(d) >> 16);
                }
                *(bf16x8*)(wof + tid * 96 + t * 16) = vh;
                *(bf16x8*)(wof + tid * 96 + 32 + t * 16) = vl;
            }
#pragma unroll
            for (int t = 0; t < 2; ++t) {
                f32x4 cb;
#pragma unroll
                for (int r = 0; r < 4; ++r) {
                    int ch = t * 16 + kc * 4 + r;
                    float v = 0.0f;
                    if (ch < 18) v = b_offset[ch];
                    else if (ch < KD) v = b_mask[ch - 18];
                    cb[r] = v;
                }
                *(f32x4*)(wof + tid * 96 + 64 + t * 16) = cb;
            }
        }
        return;
    }

    const int p0 = (blockIdx.x * 256 + tid) * 4;   // 4 consecutive pixels
    if (p0 >= npix) return;
    const int bb = p0 >> 16;
    const int q  = p0 & 0xffff;
    const float* xb = x + (size_t)bb * (3 * 65536) + q;
    f32x4 r0 = *(const f32x4*)(xb);
    f32x4 r1 = *(const f32x4*)(xb + 65536);
    f32x4 r2 = *(const f32x4*)(xb + 131072);

    bf16x8 v0 = {f2bf(r0[0]), f2bf(r1[0]), f2bf(r2[0]), 0,
                 f2bf(r0[1]), f2bf(r1[1]), f2bf(r2[1]), 0};
    bf16x8 v1 = {f2bf(r0[2]), f2bf(r1[2]), f2bf(r2[2]), 0,
                 f2bf(r0[3]), f2bf(r1[3]), f2bf(r2[3]), 0};
    short* A = xbf + (size_t)p0 * 4;
    *(bf16x8*)A       = v0;
    *(bf16x8*)(A + 8) = v1;
}

// ================================ main =========================================
__global__ __launch_bounds__(256) void dcn_main(
    const float* __restrict__ x,     // (B,3,256,256) f32 (slow-path only)
    const short* __restrict__ xbf,   // (B,H,W,4) bf16 pixel-major
    const short* __restrict__ wcf,
    const char*  __restrict__ wof,
    float* __restrict__ out)         // (B,64,256,256)
{
    __shared__ __align__(16) char LDSBUF[XST + 7 * XSLOT * 2];   // 24576 + 14336 = 38912 B

    const int tid = threadIdx.x;
    const int j = tid;
    const int i = blockIdx.x & (HH - 1);
    const int b = blockIdx.x >> 8;
    const int lane = tid & 63;
    const int wv = tid >> 6;
    const int fm = lane & 15;
    const int kc = lane >> 4;

    char* wbase = LDSBUF + wv * WRB;
    short* patchS = (short*)wbase;
    short* xs = (short*)(LDSBUF + XST);   // [7 slots][256 px][4 shorts] bf16

    const float* xb = x + (size_t)b * (CC * HH * WW);
    const short* xrow = xbf + (size_t)b * (HH * WW * 4);

    // ---- phase 0: stage rows i-3..i+3 (clamped) from prepacked bf16 ----
    u32x2 st[7];
#pragma unroll
    for (int s = 0; s < 7; ++s) {
        int gr = min(max(i - 3 + s, 0), HH - 1);
        st[s] = *(const u32x2*)(xrow + ((size_t)gr * WW + tid) * 4);
    }
#pragma unroll
    for (int s = 0; s < 7; ++s) {
        *(u32x2*)(xs + s * XSLOT + tid * 4) = st[s];
    }
    __syncthreads();

    // ---- patch from LDS (9 b64 reads), zero-padded at image borders ----
    const bool yok0 = (i - 1) >= 0, yok2 = (i + 1) < HH;
    const bool xok0 = (j - 1) >= 0, xok2 = (j + 1) < WW;
    s16x4 pr[3][3];
#pragma unroll
    for (int p = 0; p < 3; ++p) {
#pragma unroll
        for (int q = 0; q < 3; ++q) {
            int xx = min(max(j + q - 1, 0), WW - 1);
            pr[p][q] = *(const s16x4*)(xs + (p + 2) * XSLOT + xx * 4);
        }
    }
    {
        short* rp = patchS + lane * PSTS;
#pragma unroll
        for (int o = 0; o < 4; ++o) {
            bf16x8 vh;
#pragma unroll
            for (int e = 0; e < 8; ++e) {
                int kd = o * 8 + e;
                if (kd < KD) {
                    int c = kd / 9, rem = kd - c * 9, p = rem / 3, q = rem - p * 3;
                    bool ok = (p == 0 ? yok0 : (p == 2 ? yok2 : true)) &&
                              (q == 0 ? xok0 : (q == 2 ? xok2 : true));
                    vh[e] = ok ? pr[p][q][c] : (short)0;
                } else {
                    vh[e] = (short)0;
                }
            }
            *(bf16x8*)(rp + o * 8) = vh;
        }
    }

    // ---- conv W fragments + bias from prepacked ws ----
    const char* wl = wof + lane * 96;
    bf16x8 whi0 = *(const bf16x8*)(wl);
    bf16x8 whi1 = *(const bf16x8*)(wl + 16);
    bf16x8 wlo0 = *(const bf16x8*)(wl + 32);
    bf16x8 wlo1 = *(const bf16x8*)(wl + 48);
    f32x4 cb0 = *(const f32x4*)(wl + 64);
    f32x4 cb1 = *(const f32x4*)(wl + 80);

    // ---- conv MFMA: D[32ch][64px] = (Whi+Wlo)*Phi + bias ----
    f32x4 dacc[4][2];
#pragma unroll
    for (int g = 0; g < 4; ++g) {
        bf16x8 phi = *(const bf16x8*)(patchS + (g * 16 + fm) * PSTS + kc * 8);
        f32x4 a0 = __builtin_amdgcn_mfma_f32_16x16x32_bf16(whi0, phi, cb0, 0, 0, 0);
        a0 = __builtin_amdgcn_mfma_f32_16x16x32_bf16(wlo0, phi, a0, 0, 0, 0);
        f32x4 a1 = __builtin_amdgcn_mfma_f32_16x16x32_bf16(whi1, phi, cb1, 0, 0, 0);
        a1 = __builtin_amdgcn_mfma_f32_16x16x32_bf16(wlo1, phi, a1, 0, 0, 0);
        dacc[g][0] = a0;
        dacc[g][1] = a1;
    }
    // D rows (80 B): 16 f32 dy/dx + dy8,dx8 @64 + z0..z3 @72; z4..z8 in M region
#pragma unroll
    for (int g = 0; g < 4; ++g) {
        int r = g * 16 + fm;
        char* dr = wbase + r * 80;
        char* mr = wbase + MOFF + r * MST;
        *(f32x4*)(dr + kc * 16) = dacc[g][0];
        f32x4 a1 = dacc[g][1];
        if (kc == 0) {
            *(f32x2*)(dr + 64) = (f32x2){a1[0], a1[1]};                 // dy8, dx8
            *(unsigned*)(dr + 72) = pack2(f2bf(a1[2]), f2bf(a1[3]));    // z0, z1
        } else if (kc == 1) {
            *(unsigned*)(dr + 76) = pack2(f2bf(a1[0]), f2bf(a1[1]));    // z2, z3
            *(unsigned*)(mr + 0) = pack2(f2bf(a1[2]), f2bf(a1[3]));     // z4, z5
        } else if (kc == 2) {
            *(unsigned*)(mr + 4) = pack2(f2bf(a1[0]), f2bf(a1[1]));     // z6, z7
            *(unsigned short*)(mr + 8) = (unsigned short)f2bf(a1[2]);   // z8
        }
    }

    // ---- read own D row + mask row fully (before S overwrites region) ----
    const char* myD = wbase + lane * 80;
    f32x4 d03 = *(const f32x4*)(myD);
    f32x4 d47 = *(const f32x4*)(myD + 16);
    f32x4 d8b = *(const f32x4*)(myD + 32);
    f32x4 dcf = *(const f32x4*)(myD + 48);
    f32x2 d8p = *(const f32x2*)(myD + 64);
    u32x2 z03 = *(const u32x2*)(myD + 72);                       // z0z1, z2z3
    const char* myM = wbase + MOFF + lane * MST;
    u32x2 z47 = *(const u32x2*)(myM);                            // z4z5, z6z7
    unsigned z8w = *(const unsigned short*)(myM + 8);

    const float dyv[9] = {d03[0], d03[2], d47[0], d47[2], d8b[0], d8b[2], dcf[0], dcf[2], d8p[0]};
    const float dxv[9] = {d03[1], d03[3], d47[1], d47[3], d8b[1], d8b[3], dcf[1], dcf[3], d8p[1]};
    const float mzf[9] = {bf2f(z03.x), bfup(z03.x), bf2f(z03.y), bfup(z03.y),
                          bf2f(z47.x), bfup(z47.x), bf2f(z47.y), bfup(z47.y), bf2f(z8w)};

    // ---- epilogue W fragments (issue early) ----
    bf16x8 afrag[4];
#pragma unroll
    for (int t2 = 0; t2 < 4; ++t2) afrag[t2] = *(const bf16x8*)(wcf + lane * 32 + t2 * 8);

    // ---- sampling: px-major bf16 LDS reads (fast) with rare global fallback ----
    const float* x0p = xb;
    const float* x1p = xb + (size_t)HH * WW;
    const float* x2p = xb + (size_t)2 * HH * WW;
    float s27[KD];
#pragma unroll
    for (int k = 0; k < KK; ++k) {
        float dy = dyv[k], dx = dxv[k];
        float msk = 1.0f / (1.0f + __expf(-mzf[k]));

        float py = (float)(i + (k / 3) - 1) + dy;
        float px = (float)(j + (k % 3) - 1) + dx;
        float y0f = floorf(py), x0f = floorf(px);
        float wy = py - y0f, wx = px - x0f;
        int y0 = (int)y0f, x0 = (int)x0f;
        int y1 = y0 + 1, x1 = x0 + 1;

        float w00 = (1.0f - wy) * (1.0f - wx);
        float w01 = (1.0f - wy) * wx;
        float w10 = wy * (1.0f - wx);
        float w11 = wy * wx;

        bool v0y = (unsigned)y0 < HH, v1y = (unsigned)y1 < HH;
        bool v0x = (unsigned)x0 < WW, v1x = (unsigned)x1 < WW;
        float f00 = (v0y && v0x) ? w00 : 0.0f;
        float f01 = (v0y && v1x) ? w01 : 0.0f;
        float f10 = (v1y && v0x) ? w10 : 0.0f;
        float f11 = (v1y && v1x) ? w11 : 0.0f;

        int y0c = min(max(y0, 0), HH - 1), y1c = min(max(y1, 0), HH - 1);
        int s0 = y0c - i + 3;
        int s1 = y1c - i + 3;
        float r0, r1, r2;
        if (__builtin_expect(__any(((unsigned)s0 > 6u) || ((unsigned)s1 > 6u)), 0)) {
            // ---- slow path: global f32 gather (exact semantics) ----
            int x0c = min(max(x0, 0), WW - 1), x1c = min(max(x1, 0), WW - 1);
            int o00 = y0c * WW + x0c, o01 = y0c * WW + x1c;
            int o10 = y1c * WW + x0c, o11 = y1c * WW + x1c;
            r0 = x0p[o00] * f00 + x0p[o01] * f01 + x0p[o10] * f10 + x0p[o11] * f11;
            r1 = x1p[o00] * f00 + x1p[o01] * f01 + x1p[o10] * f10 + x1p[o11] * f11;
            r2 = x2p[o00] * f00 + x2p[o01] * f01 + x2p[o10] * f10 + x2p[o11] * f11;
        } else {
            // ---- fast path: 4 x 8B LDS reads; clamped-x handled by weight swap ----
            int xl = min(max(x0, 0), WW - 2);
            bool sw = (x0 != xl);
            const short* p0 = xs + s0 * XSLOT + xl * 4;
            const short* p1 = xs + s1 * XSLOT + xl * 4;
            u32x2 lo0 = *(const u32x2*)p0;
            u32x2 hi0 = *(const u32x2*)(p0 + 4);
            u32x2 lo1 = *(const u32x2*)p1;
            u32x2 hi1 = *(const u32x2*)(p1 + 4);

            float a0 = sw ? f01 : f00, b0 = sw ? f00 : f01;   // weights for (lo, hi)
            float a1w = sw ? f11 : f10, b1w = sw ? f10 : f11;

            r0 = fmaf(bf2f(lo0.x), a0, fmaf(bf2f(hi0.x), b0,
                 fmaf(bf2f(lo1.x), a1w, bf2f(hi1.x) * b1w)));
            r1 = fmaf(bfup(lo0.x), a0, fmaf(bfup(hi0.x), b0,
                 fmaf(bfup(lo1.x), a1w, bfup(hi1.x) * b1w)));
            r2 = fmaf(bf2f(lo0.y), a0, fmaf(bf2f(hi0.y), b0,
                 fmaf(bf2f(lo1.y), a1w, bf2f(hi1.y) * b1w)));
        }
        s27[k]      = r0 * msk;
        s27[9 + k]  = r1 * msk;
        s27[18 + k] = r2 * msk;
    }

    // ---- S rows: stride-80 b128 writes ----
    {
        short* srow = patchS + lane * PSTS;
#pragma unroll
        for (int o = 0; o < 4; ++o) {
            bf16x8 v;
#pragma unroll
            for (int e = 0; e < 8; ++e) {
                int kd = o * 8 + e;
                v[e] = (kd < KD) ? f2bf(s27[kd]) : (short)0;
            }
            *(bf16x8*)(srow + o * 8) = v;
        }
    }

    // ---- MFMA epilogue, operand-swapped: 4 consecutive px per lane -> dwordx4 ----
    float* obase = out + ((size_t)b * OC * HH + i) * WW;
#pragma unroll
    for (int g = 0; g < 4; ++g) {
        bf16x8 sfrag = *(const bf16x8*)(patchS + (g * 16 + fm) * PSTS + kc * 8);
#pragma unroll
        for (int t2 = 0; t2 < 4; ++t2) {
            f32x4 acc = (f32x4){0.f, 0.f, 0.f, 0.f};
            acc = __builtin_amdgcn_mfma_f32_16x16x32_bf16(sfrag, afrag[t2], acc, 0, 0, 0);
            float* op = obase + (size_t)(t2 * 16 + fm) * (HH * WW) + (wv * 64 + g * 16 + kc * 4);
            *(f32x4*)op = acc;
        }
    }
}

extern "C" void kernel_launch(void* const* d_in, const int* in_sizes, int n_in,
                              void* d_out, int out_size, void* d_ws, size_t ws_size,
                              hipStream_t stream) {
    const float* x        = (const float*)d_in[0];
    const float* w_offset = (const float*)d_in[1];
    const float* b_offset = (const float*)d_in[2];
    const float* w_mask   = (const float*)d_in[3];
    const float* b_mask   = (const float*)d_in[4];
    const float* w_conv   = (const float*)d_in[5];
    float* out = (float*)d_out;

    int B = in_sizes[0] / (CC * HH * WW);   // 16
    int npix = B * HH * WW;                 // 1,048,576

    // ws layout: xbf (npix*8 B) | wcf 4096 B | wof 6144 B
    short* xbf = (short*)d_ws;
    short* wcf = (short*)((char*)d_ws + (size_t)npix * 8);
    char*  wof = (char*)d_ws + (size_t)npix * 8 + 4096;

    int nb = (npix + 1023) / 1024;          // 4 px per thread
    hipLaunchKernelGGL(dcn_prep, dim3(nb + 1), dim3(256), 0, stream,
                       x, w_offset, b_offset, w_mask, b_mask, w_conv,
                       xbf, wcf, wof, npix);
    hipLaunchKernelGGL(dcn_main, dim3(B * HH), dim3(256), 0, stream,
                       x, xbf, wcf, wof, out);
}

// Round 11
// 75.735 us; speedup vs baseline: 9.2848x; 1.0013x over previous
//
#include <hip/hip_runtime.h>
#include <hip/hip_bf16.h>

#define HH 256
#define WW 256
#define CC 3
#define KK 9
#define OC 64
#define KD 27
#define PSTS 40    // patch/D/S row stride in shorts (80 B) — proven 0-conflict b128 pattern
#define MOFF 5120  // mask-z region offset within per-wave LDS region
#define MST 16     // mask row stride bytes (z4..z8, 10 B used)
#define WRB 6144   // per-wave LDS bytes: 5120 (64 x 80B) + 1024 (64 x 16B)
#define XST (4 * WRB)   // xstage offset in LDSBUF = 24576
#define XSLOT 1024      // shorts per staged slot (256 px * 4 shorts)
#define ROWS 4          // output rows per block
#define SLOTS 10        // staged rows: r0-3 .. r0+6

typedef __attribute__((ext_vector_type(8))) short bf16x8;
typedef __attribute__((ext_vector_type(4))) short s16x4;
typedef __attribute__((ext_vector_type(4))) float f32x4;
typedef __attribute__((ext_vector_type(2))) float f32x2;
typedef __attribute__((ext_vector_type(2))) unsigned int u32x2;

// hardware RNE f32 -> bf16
static __device__ __forceinline__ short f2bf(float f) {
    __hip_bfloat16 h = __float2bfloat16(f);
    return __builtin_bit_cast(short, h);
}
static __device__ __forceinline__ unsigned pack2(short a, short b) {
    return (unsigned)(unsigned short)a | ((unsigned)(unsigned short)b << 16);
}
static __device__ __forceinline__ float bf2f(unsigned w) {   // low 16 bits
    return __uint_as_float(w << 16);
}
static __device__ __forceinline__ float bfup(unsigned w) {   // high 16 bits
    return __uint_as_float(w & 0xffff0000u);
}

// ===================== prep: bf16 pixel-major x copy + weight fragments ========
__global__ __launch_bounds__(256) void dcn_prep(
    const float* __restrict__ x,
    const float* __restrict__ w_offset, const float* __restrict__ b_offset,
    const float* __restrict__ w_mask,   const float* __restrict__ b_mask,
    const float* __restrict__ w_conv,
    short* __restrict__ xbf, short* __restrict__ wcf, char* __restrict__ wof,
    int npix)
{
    const int tid = threadIdx.x;
    if (blockIdx.x == gridDim.x - 1) {
        if (tid < 64) {
            const int fm = tid & 15, kc = tid >> 4;
#pragma unroll
            for (int t = 0; t < 4; ++t) {
                bf16x8 v;
#pragma unroll
                for (int e = 0; e < 8; ++e) {
                    int kd = kc * 8 + e;
                    v[e] = (kd < KD) ? f2bf(w_conv[(t * 16 + fm) * KD + kd]) : (short)0;
                }
                *(bf16x8*)(wcf + tid * 32 + t * 8) = v;
            }
#pragma unroll
            for (int t = 0; t < 2; ++t) {
                int ch = t * 16 + fm;
                bf16x8 vh, vl;
#pragma unroll
                for (int e = 0; e < 8; ++e) {
                    int kd = kc * 8 + e;
                    float val = 0.0f;
                    if (kd < KD) {
                        if (ch < 18) val = w_offset[ch * KD + kd];
                        else if (ch < KD) val = w_mask[(ch - 18) * KD + kd];
                    }
                    unsigned u = __float_as_uint(val);
                    vh[e] = (short)(u >> 16);
                    float d = val - __uint_as_float(u & 0xffff0000u);
                    vl[e] = (short)(__float_as_uint(d) >> 16);
                }
                *(bf16x8*)(wof + tid * 96 + t * 16) = vh;
                *(bf16x8*)(wof + tid * 96 + 32 + t * 16) = vl;
            }
#pragma unroll
            for (int t = 0; t < 2; ++t) {
                f32x4 cb;
#pragma unroll
                for (int r = 0; r < 4; ++r) {
                    int ch = t * 16 + kc * 4 + r;
                    float v = 0.0f;
                    if (ch < 18) v = b_offset[ch];
                    else if (ch < KD) v = b_mask[ch - 18];
                    cb[r] = v;
                }
                *(f32x4*)(wof + tid * 96 + 64 + t * 16) = cb;
            }
        }
        return;
    }

    const int p0 = (blockIdx.x * 256 + tid) * 4;   // 4 consecutive pixels
    if (p0 >= npix) return;
    const int bb = p0 >> 16;
    const int q  = p0 & 0xffff;
    const float* xb = x + (size_t)bb * (3 * 65536) + q;
    f32x4 r0 = *(const f32x4*)(xb);
    f32x4 r1 = *(const f32x4*)(xb + 65536);
    f32x4 r2 = *(const f32x4*)(xb + 131072);

    bf16x8 v0 = {f2bf(r0[0]), f2bf(r1[0]), f2bf(r2[0]), 0,
                 f2bf(r0[1]), f2bf(r1[1]), f2bf(r2[1]), 0};
    bf16x8 v1 = {f2bf(r0[2]), f2bf(r1[2]), f2bf(r2[2]), 0,
                 f2bf(r0[3]), f2bf(r1[3]), f2bf(r2[3]), 0};
    short* A = xbf + (size_t)p0 * 4;
    *(bf16x8*)A       = v0;
    *(bf16x8*)(A + 8) = v1;
}

// ================================ main =========================================
// One block = 4 consecutive output rows (r0..r0+3) of one image.
__global__ __launch_bounds__(256) void dcn_main(
    const float* __restrict__ x,     // (B,3,256,256) f32 (slow-path only)
    const short* __restrict__ xbf,   // (B,H,W,4) bf16 pixel-major
    const short* __restrict__ wcf,
    const char*  __restrict__ wof,
    float* __restrict__ out)         // (B,64,256,256)
{
    __shared__ __align__(16) char LDSBUF[XST + SLOTS * XSLOT * 2];   // 24576+20480=45056

    const int tid = threadIdx.x;
    const int j = tid;
    const int r0 = (blockIdx.x & 63) * ROWS;
    const int b = blockIdx.x >> 6;
    const int lane = tid & 63;
    const int wv = tid >> 6;
    const int fm = lane & 15;
    const int kc = lane >> 4;

    char* wbase = LDSBUF + wv * WRB;
    short* patchS = (short*)wbase;
    short* xs = (short*)(LDSBUF + XST);   // [10 slots][256 px][4 shorts] bf16

    const float* xb = x + (size_t)b * (CC * HH * WW);
    const short* xrow = xbf + (size_t)b * (HH * WW * 4);

    // ---- phase 0: stage rows r0-3 .. r0+6 (clamped) from prepacked bf16 ----
    {
        u32x2 st[SLOTS];
#pragma unroll
        for (int s = 0; s < SLOTS; ++s) {
            int gr = min(max(r0 - 3 + s, 0), HH - 1);
            st[s] = *(const u32x2*)(xrow + ((size_t)gr * WW + tid) * 4);
        }
#pragma unroll
        for (int s = 0; s < SLOTS; ++s) {
            *(u32x2*)(xs + s * XSLOT + tid * 4) = st[s];
        }
    }
    __syncthreads();

    // ---- conv W fragments + bias (loaded once for all 4 rows) ----
    const char* wl = wof + lane * 96;
    bf16x8 whi0 = *(const bf16x8*)(wl);
    bf16x8 whi1 = *(const bf16x8*)(wl + 16);
    bf16x8 wlo0 = *(const bf16x8*)(wl + 32);
    bf16x8 wlo1 = *(const bf16x8*)(wl + 48);
    f32x4 cb0 = *(const f32x4*)(wl + 64);
    f32x4 cb1 = *(const f32x4*)(wl + 80);
    bf16x8 afrag[4];
#pragma unroll
    for (int t2 = 0; t2 < 4; ++t2) afrag[t2] = *(const bf16x8*)(wcf + lane * 32 + t2 * 8);

    const float* x0p = xb;
    const float* x1p = xb + (size_t)HH * WW;
    const float* x2p = xb + (size_t)2 * HH * WW;

#pragma unroll 1
    for (int d = 0; d < ROWS; ++d) {
        const int ri = r0 + d;

        // ---- patch from LDS (9 b64 reads), zero-padded at image borders ----
        const bool yok0 = (ri - 1) >= 0, yok2 = (ri + 1) < HH;
        const bool xok0 = (j - 1) >= 0, xok2 = (j + 1) < WW;
        s16x4 pr[3][3];
#pragma unroll
        for (int p = 0; p < 3; ++p) {
#pragma unroll
            for (int q = 0; q < 3; ++q) {
                int xx = min(max(j + q - 1, 0), WW - 1);
                pr[p][q] = *(const s16x4*)(xs + (d + p + 2) * XSLOT + xx * 4);
            }
        }
        {
            short* rp = patchS + lane * PSTS;
#pragma unroll
            for (int o = 0; o < 4; ++o) {
                bf16x8 vh;
#pragma unroll
                for (int e = 0; e < 8; ++e) {
                    int kd = o * 8 + e;
                    if (kd < KD) {
                        int c = kd / 9, rem = kd - c * 9, p = rem / 3, q = rem - p * 3;
                        bool ok = (p == 0 ? yok0 : (p == 2 ? yok2 : true)) &&
                                  (q == 0 ? xok0 : (q == 2 ? xok2 : true));
                        vh[e] = ok ? pr[p][q][c] : (short)0;
                    } else {
                        vh[e] = (short)0;
                    }
                }
                *(bf16x8*)(rp + o * 8) = vh;
            }
        }

        // ---- conv MFMA: D[32ch][64px] = (Whi+Wlo)*Phi + bias ----
        f32x4 dacc[4][2];
#pragma unroll
        for (int g = 0; g < 4; ++g) {
            bf16x8 phi = *(const bf16x8*)(patchS + (g * 16 + fm) * PSTS + kc * 8);
            f32x4 a0 = __builtin_amdgcn_mfma_f32_16x16x32_bf16(whi0, phi, cb0, 0, 0, 0);
            a0 = __builtin_amdgcn_mfma_f32_16x16x32_bf16(wlo0, phi, a0, 0, 0, 0);
            f32x4 a1 = __builtin_amdgcn_mfma_f32_16x16x32_bf16(whi1, phi, cb1, 0, 0, 0);
            a1 = __builtin_amdgcn_mfma_f32_16x16x32_bf16(wlo1, phi, a1, 0, 0, 0);
            dacc[g][0] = a0;
            dacc[g][1] = a1;
        }
        // D rows (80 B): 16 f32 dy/dx + dy8,dx8 @64 + z0..z3 @72; z4..z8 in M region
#pragma unroll
        for (int g = 0; g < 4; ++g) {
            int r = g * 16 + fm;
            char* dr = wbase + r * 80;
            char* mr = wbase + MOFF + r * MST;
            *(f32x4*)(dr + kc * 16) = dacc[g][0];
            f32x4 a1 = dacc[g][1];
            if (kc == 0) {
                *(f32x2*)(dr + 64) = (f32x2){a1[0], a1[1]};                 // dy8, dx8
                *(unsigned*)(dr + 72) = pack2(f2bf(a1[2]), f2bf(a1[3]));    // z0, z1
            } else if (kc == 1) {
                *(unsigned*)(dr + 76) = pack2(f2bf(a1[0]), f2bf(a1[1]));    // z2, z3
                *(unsigned*)(mr + 0) = pack2(f2bf(a1[2]), f2bf(a1[3]));     // z4, z5
            } else if (kc == 2) {
                *(unsigned*)(mr + 4) = pack2(f2bf(a1[0]), f2bf(a1[1]));     // z6, z7
                *(unsigned short*)(mr + 8) = (unsigned short)f2bf(a1[2]);   // z8
            }
        }

        // ---- read own D row + mask row fully (before S overwrites region) ----
        const char* myD = wbase + lane * 80;
        f32x4 d03 = *(const f32x4*)(myD);
        f32x4 d47 = *(const f32x4*)(myD + 16);
        f32x4 d8b = *(const f32x4*)(myD + 32);
        f32x4 dcf = *(const f32x4*)(myD + 48);
        f32x2 d8p = *(const f32x2*)(myD + 64);
        u32x2 z03 = *(const u32x2*)(myD + 72);
        const char* myM = wbase + MOFF + lane * MST;
        u32x2 z47 = *(const u32x2*)(myM);
        unsigned z8w = *(const unsigned short*)(myM + 8);

        const float dyv[9] = {d03[0], d03[2], d47[0], d47[2], d8b[0], d8b[2], dcf[0], dcf[2], d8p[0]};
        const float dxv[9] = {d03[1], d03[3], d47[1], d47[3], d8b[1], d8b[3], dcf[1], dcf[3], d8p[1]};
        const float mzf[9] = {bf2f(z03.x), bfup(z03.x), bf2f(z03.y), bfup(z03.y),
                              bf2f(z47.x), bfup(z47.x), bf2f(z47.y), bfup(z47.y), bf2f(z8w)};

        // ---- sampling: px-major bf16 LDS reads (fast) with rare global fallback ----
        float s27[KD];
#pragma unroll
        for (int k = 0; k < KK; ++k) {
            float dy = dyv[k], dx = dxv[k];
            float msk = 1.0f / (1.0f + __expf(-mzf[k]));

            float py = (float)(ri + (k / 3) - 1) + dy;
            float px = (float)(j + (k % 3) - 1) + dx;
            float y0f = floorf(py), x0f = floorf(px);
            float wy = py - y0f, wx = px - x0f;
            int y0 = (int)y0f, x0 = (int)x0f;
            int y1 = y0 + 1, x1 = x0 + 1;

            float w00 = (1.0f - wy) * (1.0f - wx);
            float w01 = (1.0f - wy) * wx;
            float w10 = wy * (1.0f - wx);
            float w11 = wy * wx;

            bool v0y = (unsigned)y0 < HH, v1y = (unsigned)y1 < HH;
            bool v0x = (unsigned)x0 < WW, v1x = (unsigned)x1 < WW;
            float f00 = (v0y && v0x) ? w00 : 0.0f;
            float f01 = (v0y && v1x) ? w01 : 0.0f;
            float f10 = (v1y && v0x) ? w10 : 0.0f;
            float f11 = (v1y && v1x) ? w11 : 0.0f;

            int y0c = min(max(y0, 0), HH - 1), y1c = min(max(y1, 0), HH - 1);
            int s0 = y0c - r0 + 3;       // slot index in 0..9 window
            int s1 = y1c - r0 + 3;
            float r0v_, r1v_, r2v_;
            if (__builtin_expect(__any(((unsigned)s0 > (SLOTS - 1)) ||
                                       ((unsigned)s1 > (SLOTS - 1))), 0)) {
                // ---- slow path: global f32 gather (exact semantics) ----
                int x0c = min(max(x0, 0), WW - 1), x1c = min(max(x1, 0), WW - 1);
                int o00 = y0c * WW + x0c, o01 = y0c * WW + x1c;
                int o10 = y1c * WW + x0c, o11 = y1c * WW + x1c;
                r0v_ = x0p[o00] * f00 + x0p[o01] * f01 + x0p[o10] * f10 + x0p[o11] * f11;
                r1v_ = x1p[o00] * f00 + x1p[o01] * f01 + x1p[o10] * f10 + x1p[o11] * f11;
                r2v_ = x2p[o00] * f00 + x2p[o01] * f01 + x2p[o10] * f10 + x2p[o11] * f11;
            } else {
                // ---- fast path: 4 x 8B LDS reads; clamped-x handled by weight swap ----
                int xl = min(max(x0, 0), WW - 2);
                bool sw = (x0 != xl);
                const short* p0 = xs + s0 * XSLOT + xl * 4;
                const short* p1 = xs + s1 * XSLOT + xl * 4;
                u32x2 lo0 = *(const u32x2*)p0;
                u32x2 hi0 = *(const u32x2*)(p0 + 4);
                u32x2 lo1 = *(const u32x2*)p1;
                u32x2 hi1 = *(const u32x2*)(p1 + 4);

                float a0 = sw ? f01 : f00, b0 = sw ? f00 : f01;
                float a1w = sw ? f11 : f10, b1w = sw ? f10 : f11;

                r0v_ = fmaf(bf2f(lo0.x), a0, fmaf(bf2f(hi0.x), b0,
                       fmaf(bf2f(lo1.x), a1w, bf2f(hi1.x) * b1w)));
                r1v_ = fmaf(bfup(lo0.x), a0, fmaf(bfup(hi0.x), b0,
                       fmaf(bfup(lo1.x), a1w, bfup(hi1.x) * b1w)));
                r2v_ = fmaf(bf2f(lo0.y), a0, fmaf(bf2f(hi0.y), b0,
                       fmaf(bf2f(lo1.y), a1w, bf2f(hi1.y) * b1w)));
            }
            s27[k]      = r0v_ * msk;
            s27[9 + k]  = r1v_ * msk;
            s27[18 + k] = r2v_ * msk;
        }

        // ---- S rows: stride-80 b128 writes ----
        {
            short* srow = patchS + lane * PSTS;
#pragma unroll
            for (int o = 0; o < 4; ++o) {
                bf16x8 v;
#pragma unroll
                for (int e = 0; e < 8; ++e) {
                    int kd = o * 8 + e;
                    v[e] = (kd < KD) ? f2bf(s27[kd]) : (short)0;
                }
                *(bf16x8*)(srow + o * 8) = v;
            }
        }

        // ---- MFMA epilogue, operand-swapped: 4 consecutive px per lane ----
        float* obase = out + ((size_t)b * OC * HH + ri) * WW;
#pragma unroll
        for (int g = 0; g < 4; ++g) {
            bf16x8 sfrag = *(const bf16x8*)(patchS + (g * 16 + fm) * PSTS + kc * 8);
#pragma unroll
            for (int t2 = 0; t2 < 4; ++t2) {
                f32x4 acc = (f32x4){0.f, 0.f, 0.f, 0.f};
                acc = __builtin_amdgcn_mfma_f32_16x16x32_bf16(sfrag, afrag[t2], acc, 0, 0, 0);
                float* op = obase + (size_t)(t2 * 16 + fm) * (HH * WW) + (wv * 64 + g * 16 + kc * 4);
                *(f32x4*)op = acc;
            }
        }
    }
}

extern "C" void kernel_launch(void* const* d_in, const int* in_sizes, int n_in,
                              void* d_out, int out_size, void* d_ws, size_t ws_size,
                              hipStream_t stream) {
    const float* x        = (const float*)d_in[0];
    const float* w_offset = (const float*)d_in[1];
    const float* b_offset = (const float*)d_in[2];
    const float* w_mask   = (const float*)d_in[3];
    const float* b_mask   = (const float*)d_in[4];
    const float* w_conv   = (const float*)d_in[5];
    float* out = (float*)d_out;

    int B = in_sizes[0] / (CC * HH * WW);   // 16
    int npix = B * HH * WW;                 // 1,048,576

    // ws layout: xbf (npix*8 B) | wcf 4096 B | wof 6144 B
    short* xbf = (short*)d_ws;
    short* wcf = (short*)((char*)d_ws + (size_t)npix * 8);
    char*  wof = (char*)d_ws + (size_t)npix * 8 + 4096;

    int nb = (npix + 1023) / 1024;          // 4 px per thread
    hipLaunchKernelGGL(dcn_prep, dim3(nb + 1), dim3(256), 0, stream,
                       x, w_offset, b_offset, w_mask, b_mask, w_conv,
                       xbf, wcf, wof, npix);
    hipLaunchKernelGGL(dcn_main, dim3(B * (HH / ROWS)), dim3(256), 0, stream,
                       x, xbf, wcf, wof, out);
}

// Round 12
// 72.837 us; speedup vs baseline: 9.6542x; 1.0398x over previous
//
#include <hip/hip_runtime.h>
#include <hip/hip_bf16.h>

#define HH 256
#define WW 256
#define CC 3
#define KK 9
#define OC 64
#define KD 27
#define PSTS 40    // patch/D/S row stride in shorts (80 B) — proven 0-conflict b128 pattern
#define WRB 5120   // per-wave LDS bytes: 64 rows x 80B (D-tail packed in bytes 64..79)
#define XST (4 * WRB)   // xstage offset in LDSBUF = 20480
#define XSLOT 1024      // shorts per staged slot (256 px * 4 shorts)
#define ROWS 2          // output rows per block
#define SLOTS 8         // staged rows: r0-3 .. r0+4

typedef __attribute__((ext_vector_type(8))) short bf16x8;
typedef __attribute__((ext_vector_type(4))) short s16x4;
typedef __attribute__((ext_vector_type(4))) float f32x4;
typedef __attribute__((ext_vector_type(2))) float f32x2;
typedef __attribute__((ext_vector_type(2))) unsigned int u32x2;
typedef __attribute__((ext_vector_type(4))) unsigned int u32x4;

// hardware RNE f32 -> bf16
static __device__ __forceinline__ short f2bf(float f) {
    __hip_bfloat16 h = __float2bfloat16(f);
    return __builtin_bit_cast(short, h);
}
static __device__ __forceinline__ unsigned pack2(short a, short b) {
    return (unsigned)(unsigned short)a | ((unsigned)(unsigned short)b << 16);
}
static __device__ __forceinline__ float bf2f(unsigned w) {   // low 16 bits
    return __uint_as_float(w << 16);
}
static __device__ __forceinline__ float bfup(unsigned w) {   // high 16 bits
    return __uint_as_float(w & 0xffff0000u);
}
static __device__ __forceinline__ unsigned q8(float z) {     // sigmoid -> u8
    float s = 1.0f / (1.0f + __expf(-z));
    return (unsigned)__builtin_rintf(s * 255.0f);
}

// ===================== prep: bf16 pixel-major x copy + weight fragments ========
__global__ __launch_bounds__(256) void dcn_prep(
    const float* __restrict__ x,
    const float* __restrict__ w_offset, const float* __restrict__ b_offset,
    const float* __restrict__ w_mask,   const float* __restrict__ b_mask,
    const float* __restrict__ w_conv,
    short* __restrict__ xbf, short* __restrict__ wcf, char* __restrict__ wof,
    int npix)
{
    const int tid = threadIdx.x;
    if (blockIdx.x == gridDim.x - 1) {
        if (tid < 64) {
            const int fm = tid & 15, kc = tid >> 4;
#pragma unroll
            for (int t = 0; t < 4; ++t) {
                bf16x8 v;
#pragma unroll
                for (int e = 0; e < 8; ++e) {
                    int kd = kc * 8 + e;
                    v[e] = (kd < KD) ? f2bf(w_conv[(t * 16 + fm) * KD + kd]) : (short)0;
                }
                *(bf16x8*)(wcf + tid * 32 + t * 8) = v;
            }
#pragma unroll
            for (int t = 0; t < 2; ++t) {
                int ch = t * 16 + fm;
                bf16x8 vh, vl;
#pragma unroll
                for (int e = 0; e < 8; ++e) {
                    int kd = kc * 8 + e;
                    float val = 0.0f;
                    if (kd < KD) {
                        if (ch < 18) val = w_offset[ch * KD + kd];
                        else if (ch < KD) val = w_mask[(ch - 18) * KD + kd];
                    }
                    unsigned u = __float_as_uint(val);
                    vh[e] = (short)(u >> 16);
                    float d = val - __uint_as_float(u & 0xffff0000u);
                    vl[e] = (short)(__float_as_uint(d) >> 16);
                }
                *(bf16x8*)(wof + tid * 96 + t * 16) = vh;
                *(bf16x8*)(wof + tid * 96 + 32 + t * 16) = vl;
            }
#pragma unroll
            for (int t = 0; t < 2; ++t) {
                f32x4 cb;
#pragma unroll
                for (int r = 0; r < 4; ++r) {
                    int ch = t * 16 + kc * 4 + r;
                    float v = 0.0f;
                    if (ch < 18) v = b_offset[ch];
                    else if (ch < KD) v = b_mask[ch - 18];
                    cb[r] = v;
                }
                *(f32x4*)(wof + tid * 96 + 64 + t * 16) = cb;
            }
        }
        return;
    }

    const int p0 = (blockIdx.x * 256 + tid) * 4;   // 4 consecutive pixels
    if (p0 >= npix) return;
    const int bb = p0 >> 16;
    const int q  = p0 & 0xffff;
    const float* xb = x + (size_t)bb * (3 * 65536) + q;
    f32x4 r0 = *(const f32x4*)(xb);
    f32x4 r1 = *(const f32x4*)(xb + 65536);
    f32x4 r2 = *(const f32x4*)(xb + 131072);

    bf16x8 v0 = {f2bf(r0[0]), f2bf(r1[0]), f2bf(r2[0]), 0,
                 f2bf(r0[1]), f2bf(r1[1]), f2bf(r2[1]), 0};
    bf16x8 v1 = {f2bf(r0[2]), f2bf(r1[2]), f2bf(r2[2]), 0,
                 f2bf(r0[3]), f2bf(r1[3]), f2bf(r2[3]), 0};
    short* A = xbf + (size_t)p0 * 4;
    *(bf16x8*)A       = v0;
    *(bf16x8*)(A + 8) = v1;
}

// ================================ main =========================================
// One block = 2 consecutive output rows of one image. 36864 B LDS -> 4 blk/CU.
__global__ __launch_bounds__(256, 4) void dcn_main(
    const float* __restrict__ x,     // (B,3,256,256) f32 (slow-path only)
    const short* __restrict__ xbf,   // (B,H,W,4) bf16 pixel-major
    const short* __restrict__ wcf,
    const char*  __restrict__ wof,
    float* __restrict__ out)         // (B,64,256,256)
{
    __shared__ __align__(16) char LDSBUF[XST + SLOTS * XSLOT * 2];   // 20480+16384=36864

    const int tid = threadIdx.x;
    const int j = tid;
    const int r0 = (blockIdx.x & 127) * ROWS;
    const int b = blockIdx.x >> 7;
    const int lane = tid & 63;
    const int wv = tid >> 6;
    const int fm = lane & 15;
    const int kc = lane >> 4;

    char* wbase = LDSBUF + wv * WRB;
    short* patchS = (short*)wbase;
    short* xs = (short*)(LDSBUF + XST);   // [8 slots][256 px][4 shorts] bf16

    const float* xb = x + (size_t)b * (CC * HH * WW);
    const short* xrow = xbf + (size_t)b * (HH * WW * 4);

    // ---- phase 0: stage rows r0-3 .. r0+4 (clamped) from prepacked bf16 ----
    {
        u32x2 st[SLOTS];
#pragma unroll
        for (int s = 0; s < SLOTS; ++s) {
            int gr = min(max(r0 - 3 + s, 0), HH - 1);
            st[s] = *(const u32x2*)(xrow + ((size_t)gr * WW + tid) * 4);
        }
#pragma unroll
        for (int s = 0; s < SLOTS; ++s) {
            *(u32x2*)(xs + s * XSLOT + tid * 4) = st[s];
        }
    }
    __syncthreads();

    // ---- conv W fragments + bias (loaded once) ----
    const char* wl = wof + lane * 96;
    bf16x8 whi0 = *(const bf16x8*)(wl);
    bf16x8 whi1 = *(const bf16x8*)(wl + 16);
    bf16x8 wlo0 = *(const bf16x8*)(wl + 32);
    bf16x8 wlo1 = *(const bf16x8*)(wl + 48);
    f32x4 cb0 = *(const f32x4*)(wl + 64);
    f32x4 cb1 = *(const f32x4*)(wl + 80);
    bf16x8 afrag[4];
#pragma unroll
    for (int t2 = 0; t2 < 4; ++t2) afrag[t2] = *(const bf16x8*)(wcf + lane * 32 + t2 * 8);

    const float* x0p = xb;
    const float* x1p = xb + (size_t)HH * WW;
    const float* x2p = xb + (size_t)2 * HH * WW;

#pragma unroll 1
    for (int d = 0; d < ROWS; ++d) {
        const int ri = r0 + d;

        // ---- patch from LDS (9 b64 reads), zero-padded at image borders ----
        const bool yok0 = (ri - 1) >= 0, yok2 = (ri + 1) < HH;
        const bool xok0 = (j - 1) >= 0, xok2 = (j + 1) < WW;
        s16x4 pr[3][3];
#pragma unroll
        for (int p = 0; p < 3; ++p) {
#pragma unroll
            for (int q = 0; q < 3; ++q) {
                int xx = min(max(j + q - 1, 0), WW - 1);
                pr[p][q] = *(const s16x4*)(xs + (d + p + 2) * XSLOT + xx * 4);
            }
        }
        {
            short* rp = patchS + lane * PSTS;
#pragma unroll
            for (int o = 0; o < 4; ++o) {
                bf16x8 vh;
#pragma unroll
                for (int e = 0; e < 8; ++e) {
                    int kd = o * 8 + e;
                    if (kd < KD) {
                        int c = kd / 9, rem = kd - c * 9, p = rem / 3, q = rem - p * 3;
                        bool ok = (p == 0 ? yok0 : (p == 2 ? yok2 : true)) &&
                                  (q == 0 ? xok0 : (q == 2 ? xok2 : true));
                        vh[e] = ok ? pr[p][q][c] : (short)0;
                    } else {
                        vh[e] = (short)0;
                    }
                }
                *(bf16x8*)(rp + o * 8) = vh;
            }
        }

        // ---- conv MFMA: D[32ch][64px] = (Whi+Wlo)*Phi + bias ----
        f32x4 dacc[4][2];
#pragma unroll
        for (int g = 0; g < 4; ++g) {
            bf16x8 phi = *(const bf16x8*)(patchS + (g * 16 + fm) * PSTS + kc * 8);
            f32x4 a0 = __builtin_amdgcn_mfma_f32_16x16x32_bf16(whi0, phi, cb0, 0, 0, 0);
            a0 = __builtin_amdgcn_mfma_f32_16x16x32_bf16(wlo0, phi, a0, 0, 0, 0);
            f32x4 a1 = __builtin_amdgcn_mfma_f32_16x16x32_bf16(whi1, phi, cb1, 0, 0, 0);
            a1 = __builtin_amdgcn_mfma_f32_16x16x32_bf16(wlo1, phi, a1, 0, 0, 0);
            dacc[g][0] = a0;
            dacc[g][1] = a1;
        }
        // D rows (80 B): 16 f32 dy/dx (k0..7) @0..63; tail @64: dy8dx8 bf16 (4B),
        // m0..m8 u8 @68..76 (sigmoid applied at write time)
#pragma unroll
        for (int g = 0; g < 4; ++g) {
            int r = g * 16 + fm;
            char* dr = wbase + r * 80;
            *(f32x4*)(dr + kc * 16) = dacc[g][0];
            f32x4 a1 = dacc[g][1];
            if (kc == 0) {          // ch16..19 = dy8, dx8, z0, z1
                *(unsigned*)(dr + 64) = pack2(f2bf(a1[0]), f2bf(a1[1]));
                *(unsigned short*)(dr + 68) = (unsigned short)(q8(a1[2]) | (q8(a1[3]) << 8));
            } else if (kc == 1) {   // ch20..23 = z2..z5
                *(unsigned short*)(dr + 70) = (unsigned short)(q8(a1[0]) | (q8(a1[1]) << 8));
                *(unsigned short*)(dr + 72) = (unsigned short)(q8(a1[2]) | (q8(a1[3]) << 8));
            } else if (kc == 2) {   // ch24..26 = z6..z8
                *(unsigned short*)(dr + 74) = (unsigned short)(q8(a1[0]) | (q8(a1[1]) << 8));
                *(unsigned short*)(dr + 76) = (unsigned short)q8(a1[2]);
            }
        }

        // ---- read own D row fully (before S overwrites region) ----
        const char* myD = wbase + lane * 80;
        f32x4 d03 = *(const f32x4*)(myD);
        f32x4 d47 = *(const f32x4*)(myD + 16);
        f32x4 d8b = *(const f32x4*)(myD + 32);
        f32x4 dcf = *(const f32x4*)(myD + 48);
        u32x4 tail = *(const u32x4*)(myD + 64);   // dy8dx8 | m0..m3 | m4..m7 | m8

        const float dyv[9] = {d03[0], d03[2], d47[0], d47[2], d8b[0], d8b[2], dcf[0], dcf[2],
                              bf2f(tail.x)};
        const float dxv[9] = {d03[1], d03[3], d47[1], d47[3], d8b[1], d8b[3], dcf[1], dcf[3],
                              bfup(tail.x)};
        const unsigned mqv[9] = {tail.y & 255u, (tail.y >> 8) & 255u, (tail.y >> 16) & 255u,
                                 tail.y >> 24, tail.z & 255u, (tail.z >> 8) & 255u,
                                 (tail.z >> 16) & 255u, tail.z >> 24, tail.w & 255u};

        // ---- sampling: px-major bf16 LDS reads (fast) with rare global fallback ----
        float s27[KD];
#pragma unroll
        for (int k = 0; k < KK; ++k) {
            float dy = dyv[k], dx = dxv[k];
            float msk = (float)mqv[k] * (1.0f / 255.0f);

            float py = (float)(ri + (k / 3) - 1) + dy;
            float px = (float)(j + (k % 3) - 1) + dx;
            float y0f = floorf(py), x0f = floorf(px);
            float wy = py - y0f, wx = px - x0f;
            int y0 = (int)y0f, x0 = (int)x0f;
            int y1 = y0 + 1, x1 = x0 + 1;

            float w00 = (1.0f - wy) * (1.0f - wx);
            float w01 = (1.0f - wy) * wx;
            float w10 = wy * (1.0f - wx);
            float w11 = wy * wx;

            bool v0y = (unsigned)y0 < HH, v1y = (unsigned)y1 < HH;
            bool v0x = (unsigned)x0 < WW, v1x = (unsigned)x1 < WW;
            float f00 = (v0y && v0x) ? w00 : 0.0f;
            float f01 = (v0y && v1x) ? w01 : 0.0f;
            float f10 = (v1y && v0x) ? w10 : 0.0f;
            float f11 = (v1y && v1x) ? w11 : 0.0f;

            int y0c = min(max(y0, 0), HH - 1), y1c = min(max(y1, 0), HH - 1);
            int s0 = y0c - r0 + 3;       // slot index, valid 0..7
            int s1 = y1c - r0 + 3;
            float r0v_, r1v_, r2v_;
            if (__builtin_expect(__any(((unsigned)s0 > (SLOTS - 1)) ||
                                       ((unsigned)s1 > (SLOTS - 1))), 0)) {
                // ---- slow path: global f32 gather (exact semantics) ----
                int x0c = min(max(x0, 0), WW - 1), x1c = min(max(x1, 0), WW - 1);
                int o00 = y0c * WW + x0c, o01 = y0c * WW + x1c;
                int o10 = y1c * WW + x0c, o11 = y1c * WW + x1c;
                r0v_ = x0p[o00] * f00 + x0p[o01] * f01 + x0p[o10] * f10 + x0p[o11] * f11;
                r1v_ = x1p[o00] * f00 + x1p[o01] * f01 + x1p[o10] * f10 + x1p[o11] * f11;
                r2v_ = x2p[o00] * f00 + x2p[o01] * f01 + x2p[o10] * f10 + x2p[o11] * f11;
            } else {
                // ---- fast path: 4 x 8B LDS reads; clamped-x handled by weight swap ----
                int xl = min(max(x0, 0), WW - 2);
                bool sw = (x0 != xl);
                const short* p0 = xs + s0 * XSLOT + xl * 4;
                const short* p1 = xs + s1 * XSLOT + xl * 4;
                u32x2 lo0 = *(const u32x2*)p0;
                u32x2 hi0 = *(const u32x2*)(p0 + 4);
                u32x2 lo1 = *(const u32x2*)p1;
                u32x2 hi1 = *(const u32x2*)(p1 + 4);

                float a0 = sw ? f01 : f00, b0 = sw ? f00 : f01;
                float a1w = sw ? f11 : f10, b1w = sw ? f10 : f11;

                r0v_ = fmaf(bf2f(lo0.x), a0, fmaf(bf2f(hi0.x), b0,
                       fmaf(bf2f(lo1.x), a1w, bf2f(hi1.x) * b1w)));
                r1v_ = fmaf(bfup(lo0.x), a0, fmaf(bfup(hi0.x), b0,
                       fmaf(bfup(lo1.x), a1w, bfup(hi1.x) * b1w)));
                r2v_ = fmaf(bf2f(lo0.y), a0, fmaf(bf2f(hi0.y), b0,
                       fmaf(bf2f(lo1.y), a1w, bf2f(hi1.y) * b1w)));
            }
            s27[k]      = r0v_ * msk;
            s27[9 + k]  = r1v_ * msk;
            s27[18 + k] = r2v_ * msk;
        }

        // ---- S rows: stride-80 b128 writes ----
        {
            short* srow = patchS + lane * PSTS;
#pragma unroll
            for (int o = 0; o < 4; ++o) {
                bf16x8 v;
#pragma unroll
                for (int e = 0; e < 8; ++e) {
                    int kd = o * 8 + e;
                    v[e] = (kd < KD) ? f2bf(s27[kd]) : (short)0;
                }
                *(bf16x8*)(srow + o * 8) = v;
            }
        }

        // ---- MFMA epilogue, operand-swapped: 4 consecutive px per lane ----
        float* obase = out + ((size_t)b * OC * HH + ri) * WW;
#pragma unroll
        for (int g = 0; g < 4; ++g) {
            bf16x8 sfrag = *(const bf16x8*)(patchS + (g * 16 + fm) * PSTS + kc * 8);
#pragma unroll
            for (int t2 = 0; t2 < 4; ++t2) {
                f32x4 acc = (f32x4){0.f, 0.f, 0.f, 0.f};
                acc = __builtin_amdgcn_mfma_f32_16x16x32_bf16(sfrag, afrag[t2], acc, 0, 0, 0);
                float* op = obase + (size_t)(t2 * 16 + fm) * (HH * WW) + (wv * 64 + g * 16 + kc * 4);
                *(f32x4*)op = acc;
            }
        }
    }
}

extern "C" void kernel_launch(void* const* d_in, const int* in_sizes, int n_in,
                              void* d_out, int out_size, void* d_ws, size_t ws_size,
                              hipStream_t stream) {
    const float* x        = (const float*)d_in[0];
    const float* w_offset = (const float*)d_in[1];
    const float* b_offset = (const float*)d_in[2];
    const float* w_mask   = (const float*)d_in[3];
    const float* b_mask   = (const float*)d_in[4];
    const float* w_conv   = (const float*)d_in[5];
    float* out = (float*)d_out;

    int B = in_sizes[0] / (CC * HH * WW);   // 16
    int npix = B * HH * WW;                 // 1,048,576

    // ws layout: xbf (npix*8 B) | wcf 4096 B | wof 6144 B
    short* xbf = (short*)d_ws;
    short* wcf = (short*)((char*)d_ws + (size_t)npix * 8);
    char*  wof = (char*)d_ws + (size_t)npix * 8 + 4096;

    int nb = (npix + 1023) / 1024;          // 4 px per thread
    hipLaunchKernelGGL(dcn_prep, dim3(nb + 1), dim3(256), 0, stream,
                       x, w_offset, b_offset, w_mask, b_mask, w_conv,
                       xbf, wcf, wof, npix);
    hipLaunchKernelGGL(dcn_main, dim3(B * (HH / ROWS)), dim3(256), 0, stream,
                       x, xbf, wcf, wof, out);
}